// Round 10
// baseline (542.390 us; speedup 1.0000x reference)
//
#include <hip/hip_runtime.h>
#include <math.h>

// ---------------- problem constants ----------------
#define D_MODEL   1024
#define D_INNER   2048
#define D_STATE   64
#define HEADDIM   128
#define NHEADS    16
#define D_CONV    4
#define BATCH     2
#define SEQLEN    4096
#define RMS_EPS   1e-5f
#define D_IN_PROJ 4240

// zxbc buffer (bf16): cols [0,2048)=z, [2048,4096)=x, [4096,4160)=B, [4160,4224)=C
#define ZX_LD     4224

#define LCHUNK    128
#define NCHUNK    (SEQLEN / LCHUNK)   // 32

typedef __attribute__((ext_vector_type(8))) short short8;
typedef __attribute__((ext_vector_type(4))) float f32x4;
typedef _Float16 half8 __attribute__((ext_vector_type(8)));

__device__ __forceinline__ ushort f2bf(float f) {
  unsigned u = __float_as_uint(f);
  u += 0x7fff + ((u >> 16) & 1);          // RNE
  return (ushort)(u >> 16);
}
__device__ __forceinline__ float bf2f(ushort h) {
  return __uint_as_float(((unsigned)h) << 16);
}
__device__ __forceinline__ ushort f2h(float f) {
  _Float16 h = (_Float16)f;               // RNE
  ushort u; __builtin_memcpy(&u, &h, 2); return u;
}
__device__ __forceinline__ void ld4(const float* p, float* d) {
  float4 v = *(const float4*)p; d[0] = v.x; d[1] = v.y; d[2] = v.z; d[3] = v.w;
}
__device__ __forceinline__ void ld4b(const ushort* p, float* d) {
  ushort4 v = *(const ushort4*)p;
  d[0] = bf2f(v.x); d[1] = bf2f(v.y); d[2] = bf2f(v.z); d[3] = bf2f(v.w);
}

// async global->LDS, 16B per lane (global_load_lds_dwordx4)
__device__ __forceinline__ void gl_lds16(const ushort* g, ushort* l) {
  __builtin_amdgcn_global_load_lds(
      (const __attribute__((address_space(1))) unsigned int*)g,
      (__attribute__((address_space(3))) unsigned int*)l, 16, 0, 0);
}

// ---------------- split fp32 -> bf16 hi/lo planes (weights) ----------------
__global__ void cvt_split(const float* __restrict__ w,
                          ushort* __restrict__ hi, ushort* __restrict__ lo, int n4) {
  int i = blockIdx.x * 256 + threadIdx.x;
  if (i >= n4) return;
  float4 v = ((const float4*)w)[i];
  ushort h0 = f2bf(v.x), h1 = f2bf(v.y), h2 = f2bf(v.z), h3 = f2bf(v.w);
  ushort l0 = f2bf(v.x - bf2f(h0)), l1 = f2bf(v.y - bf2f(h1));
  ushort l2 = f2bf(v.z - bf2f(h2)), l3 = f2bf(v.w - bf2f(h3));
  ((ushort4*)hi)[i] = make_ushort4(h0, h1, h2, h3);
  ((ushort4*)lo)[i] = make_ushort4(l0, l1, l2, l3);
}

// ---------------- fp32 -> fp16 plane ----------------
__global__ void cvt_f16(const float* __restrict__ w, ushort* __restrict__ o, int n4) {
  int i = blockIdx.x * 256 + threadIdx.x;
  if (i >= n4) return;
  float4 v = ((const float4*)w)[i];
  ((ushort4*)o)[i] = make_ushort4(f2h(v.x), f2h(v.y), f2h(v.z), f2h(v.w));
}

// --------- u: one fp32 read -> bf16 hi/lo (dt GEMM) + f16 (in-proj) ---------
__global__ void cvt_u3(const float* __restrict__ w, ushort* __restrict__ hi,
                       ushort* __restrict__ lo, ushort* __restrict__ h16, int n4) {
  int i = blockIdx.x * 256 + threadIdx.x;
  if (i >= n4) return;
  float4 v = ((const float4*)w)[i];
  ushort h0 = f2bf(v.x), h1 = f2bf(v.y), h2 = f2bf(v.z), h3 = f2bf(v.w);
  ((ushort4*)hi)[i]  = make_ushort4(h0, h1, h2, h3);
  ((ushort4*)lo)[i]  = make_ushort4(f2bf(v.x - bf2f(h0)), f2bf(v.y - bf2f(h1)),
                                    f2bf(v.z - bf2f(h2)), f2bf(v.w - bf2f(h3)));
  ((ushort4*)h16)[i] = make_ushort4(f2h(v.x), f2h(v.y), f2h(v.z), f2h(v.w));
}

// ---------------- bf16-plane split NT GEMM (single-buffered; dt GEMM only) ---
template<int BM, int BK, bool ALO, bool OBF16>
__launch_bounds__(256, 3)
__global__ void gemm_bf16p(const ushort* __restrict__ Ah, const ushort* __restrict__ Al,
                           const ushort* __restrict__ Bh, const ushort* __restrict__ Bl,
                           float* __restrict__ C, int ldc,
                           int M, int N, int ldab, int Kslice, int n1term) {
  constexpr int BN = 128;
  constexpr int NQ = BK / 8;
  constexpr int RT = BM / 32;
  constexpr int CT = 4;
  constexpr int KS = BK / 32;

  __shared__ ushort As[ALO ? 2 : 1][BM * BK];
  __shared__ ushort Bs[2][BN * BK];

  const int bn   = blockIdx.x * BN;
  if (bn >= N) return;
  const bool two = (bn >= n1term);
  const int t    = threadIdx.x;
  const int bm   = blockIdx.y * BM;
  const int kz   = blockIdx.z;
  const int kb   = kz * Kslice;
  C += (size_t)kz * M * ldc;
  const int wave = t >> 6, lane = t & 63;
  const int ml   = lane & 15, g4 = lane >> 4;
  const int sw   = ml & (NQ - 1);
  const int wr   = wave & 1, wc = wave >> 1;
  const int r0   = wr * RT * 16, c0 = wc * CT * 16;

  f32x4 acc[RT][CT];
#pragma unroll
  for (int i = 0; i < RT; ++i)
#pragma unroll
    for (int j = 0; j < CT; ++j) acc[i][j] = (f32x4){0.f, 0.f, 0.f, 0.f};

  for (int k0 = kb; k0 < kb + Kslice; k0 += BK) {
    __syncthreads();
#pragma unroll
    for (int ii = 0; ii < BM * NQ / 256; ++ii) {
      int idx = t + ii * 256;
      int row = idx / NQ, qs = idx % NQ;
      int qg  = qs ^ (row & (NQ - 1));
      size_t go = (size_t)(bm + row) * ldab + k0 + qg * 8;
      gl_lds16(Ah + go, &As[0][idx * 8]);
      if (ALO) gl_lds16(Al + go, &As[ALO ? 1 : 0][idx * 8]);
    }
#pragma unroll
    for (int ii = 0; ii < BN * NQ / 256; ++ii) {
      int idx = t + ii * 256;
      int row = idx / NQ, qs = idx % NQ;
      int qg  = qs ^ (row & (NQ - 1));
      size_t go = (size_t)(bn + row) * ldab + k0 + qg * 8;
      gl_lds16(Bh + go, &Bs[0][idx * 8]);
      if (two) gl_lds16(Bl + go, &Bs[1][idx * 8]);
    }
    __syncthreads();

#pragma unroll
    for (int ks = 0; ks < KS; ++ks) {
      const int qA = ((ks * 4 + g4) ^ sw) * 8;
      short8 ah[RT], al[RT], bh[CT], bl[CT];
#pragma unroll
      for (int i = 0; i < RT; ++i) {
        int off = (r0 + i * 16 + ml) * BK + qA;
        ah[i] = *(const short8*)&As[0][off];
        if (ALO) al[i] = *(const short8*)&As[ALO ? 1 : 0][off];
      }
#pragma unroll
      for (int j = 0; j < CT; ++j) {
        int off = (c0 + j * 16 + ml) * BK + qA;
        bh[j] = *(const short8*)&Bs[0][off];
        if (two) bl[j] = *(const short8*)&Bs[1][off];
      }
#pragma unroll
      for (int i = 0; i < RT; ++i)
#pragma unroll
        for (int j = 0; j < CT; ++j) {
          acc[i][j] = __builtin_amdgcn_mfma_f32_16x16x32_bf16(ah[i], bh[j], acc[i][j], 0, 0, 0);
          if (two)
            acc[i][j] = __builtin_amdgcn_mfma_f32_16x16x32_bf16(ah[i], bl[j], acc[i][j], 0, 0, 0);
          if (ALO)
            acc[i][j] = __builtin_amdgcn_mfma_f32_16x16x32_bf16(al[i], bh[j], acc[i][j], 0, 0, 0);
        }
    }
  }

#pragma unroll
  for (int i = 0; i < RT; ++i)
#pragma unroll
    for (int j = 0; j < CT; ++j) {
      int col = bn + c0 + j * 16 + ml;
      if (col < N) {
        int rowb = bm + r0 + i * 16 + g4 * 4;
#pragma unroll
        for (int r = 0; r < 4; ++r) {
          if (OBF16) ((ushort*)C)[(size_t)(rowb + r) * ldc + col] = f2bf(acc[i][j][r]);
          else       C[(size_t)(rowb + r) * ldc + col] = acc[i][j][r];
        }
      }
    }
}

// ---------------- single-plane FP16 NT GEMM (128-col tiles) ----------------
// PIPE=false: single-buffered, 32KB LDS -> 5 blocks/CU (160KB exact; in-proj
// grid 1280 = 5x256 CUs exact). PIPE=true: depth-2 counted-vmcnt pipeline
// (only for grid-limited >=2-block/CU call sites; 1 block/CU regressed, R9).
template<int BM, int BK, bool OBF16, bool PIPE>
__launch_bounds__(256, PIPE ? 2 : 5)
__global__ void gemm_f16(const ushort* __restrict__ Ah, const ushort* __restrict__ Bh,
                         float* __restrict__ C, int ldc,
                         int M, int N, int ldab, int Kslice) {
  constexpr int BN = 128;
  constexpr int NQ = BK / 8;
  constexpr int RT = BM / 32;
  constexpr int CT = 4;
  constexpr int KS = BK / 32;
  constexpr int NBUF = PIPE ? 2 : 1;

  __shared__ ushort As[NBUF][BM * BK];
  __shared__ ushort Bs[NBUF][BN * BK];

  const int bn   = blockIdx.x * BN;
  if (bn >= N) return;                     // padded grid.x tiles exit
  const int t    = threadIdx.x;
  const int bm   = blockIdx.y * BM;
  const int kz   = blockIdx.z;
  const int kb   = kz * Kslice;
  C += (size_t)kz * M * ldc;
  const int wave = t >> 6, lane = t & 63;
  const int ml   = lane & 15, g4 = lane >> 4;
  const int sw   = ml & (NQ - 1);
  const int wr   = wave & 1, wc = wave >> 1;
  const int r0   = wr * RT * 16, c0 = wc * CT * 16;

  f32x4 acc[RT][CT];
#pragma unroll
  for (int i = 0; i < RT; ++i)
#pragma unroll
    for (int j = 0; j < CT; ++j) acc[i][j] = (f32x4){0.f, 0.f, 0.f, 0.f};

  auto stage = [&](int k0, int buf) {
#pragma unroll
    for (int ii = 0; ii < BM * NQ / 256; ++ii) {
      int idx = t + ii * 256;
      int row = idx / NQ, qs = idx % NQ;
      int qg  = qs ^ (row & (NQ - 1));
      size_t go = (size_t)(bm + row) * ldab + k0 + qg * 8;
      gl_lds16(Ah + go, &As[buf][idx * 8]);
    }
#pragma unroll
    for (int ii = 0; ii < BN * NQ / 256; ++ii) {
      int idx = t + ii * 256;
      int row = idx / NQ, qs = idx % NQ;
      int qg  = qs ^ (row & (NQ - 1));
      size_t go = (size_t)(bn + row) * ldab + k0 + qg * 8;   // rows past N read
      gl_lds16(Bh + go, &Bs[buf][idx * 8]);                  // adjacent valid memory
    }
  };

  auto compute = [&](int buf) {
#pragma unroll
    for (int ks = 0; ks < KS; ++ks) {
      const int qA = ((ks * 4 + g4) ^ sw) * 8;
      half8 ah[RT], bh[CT];
#pragma unroll
      for (int i = 0; i < RT; ++i)
        ah[i] = *(const half8*)&As[buf][(r0 + i * 16 + ml) * BK + qA];
#pragma unroll
      for (int j = 0; j < CT; ++j)
        bh[j] = *(const half8*)&Bs[buf][(c0 + j * 16 + ml) * BK + qA];
#pragma unroll
      for (int i = 0; i < RT; ++i)
#pragma unroll
        for (int j = 0; j < CT; ++j)
          acc[i][j] = __builtin_amdgcn_mfma_f32_16x16x32_f16(ah[i], bh[j], acc[i][j], 0, 0, 0);
    }
  };

  if (PIPE) {
    const int NIT = Kslice / BK;
    stage(kb, 0);
    if (NIT > 1) stage(kb + BK, 1);
    for (int it = 0; it < NIT; ++it) {
      const int buf = it & 1;
      if (it + 1 < NIT) asm volatile("s_waitcnt vmcnt(8)" ::: "memory");
      else              asm volatile("s_waitcnt vmcnt(0)" ::: "memory");
      __builtin_amdgcn_s_barrier();        // all waves' stage(it) landed
      __builtin_amdgcn_sched_barrier(0);
      compute(buf);
      __builtin_amdgcn_sched_barrier(0);
      __builtin_amdgcn_s_barrier();        // all waves done reading buf
      __builtin_amdgcn_sched_barrier(0);
      if (it + 2 < NIT) stage(kb + (it + 2) * BK, buf);
    }
  } else {
    for (int k0 = kb; k0 < kb + Kslice; k0 += BK) {
      __syncthreads();
      stage(k0, 0);
      __syncthreads();
      compute(0);
    }
  }

#pragma unroll
  for (int i = 0; i < RT; ++i)
#pragma unroll
    for (int j = 0; j < CT; ++j) {
      int col = bn + c0 + j * 16 + ml;
      if (col < N) {
        int rowb = bm + r0 + i * 16 + g4 * 4;
#pragma unroll
        for (int r = 0; r < 4; ++r) {
          if (OBF16) ((ushort*)C)[(size_t)(rowb + r) * ldc + col] = f2bf(acc[i][j][r]);
          else       C[(size_t)(rowb + r) * ldc + col] = acc[i][j][r];
        }
      }
    }
}

// ---------------- combine split-K partials: out = P0 + P1 ----------------
__global__ void add_out(const float* __restrict__ P, float* __restrict__ out, int n4) {
  int i = blockIdx.x * 256 + threadIdx.x;
  if (i >= n4) return;
  float4 a = ((const float4*)P)[i];
  float4 b = ((const float4*)(P + (size_t)SEQLEN * D_MODEL))[i];
  ((float4*)out)[i] = make_float4(a.x + b.x, a.y + b.y, a.z + b.z, a.w + b.w);
}

// ---------------- combine dt split-K=8 partials ----------------
__global__ void add_dt(const float* __restrict__ P, float* __restrict__ dtb) {
  int i = blockIdx.x * 256 + threadIdx.x;
  if (i >= SEQLEN * NHEADS / 4) return;
  float4 s = ((const float4*)P)[i];
#pragma unroll
  for (int k = 1; k < 8; ++k) {
    float4 v = ((const float4*)(P + (size_t)k * SEQLEN * NHEADS))[i];
    s.x += v.x; s.y += v.y; s.z += v.z; s.w += v.w;
  }
  ((float4*)dtb)[i] = s;
}

// =================== SSD chunked scan on MFMA ===================
// Scan operands are single-plane FP16 (2^-11 rel): inputs come from zxbc,
// already bf16 (2^-8 rel) — higher precision downstream is wasted (R8 verified).

__device__ __forceinline__ void cum_scan(float* cum, float v, int t, float* carry) {
  int lane = t & 63;
#pragma unroll
  for (int off = 1; off < 64; off <<= 1) {
    float o = __shfl_up(v, off);
    if (lane >= off) v += o;
  }
  if (t == 63) *carry = v;
  __syncthreads();
  if (t >= 64 && t < LCHUNK) v += *carry;
  if (t < LCHUNK) cum[t] = v;
  __syncthreads();
}

// conv+silu at (l, zxbc-col): channel = col - 2048; taps read bf16 rows above.
__device__ __forceinline__ void conv4b(const ushort* __restrict__ zx,
                                       const float* __restrict__ cw,
                                       const float* __restrict__ cb,
                                       int l, int col0, float* outv) {
  const ushort* bp = zx + (size_t)l * ZX_LD + col0;
  float r3[4], r2[4], r1[4], r0[4], bb[4];
  ld4b(bp, r3);
  if (l >= 1) ld4b(bp - ZX_LD, r2);     else { r2[0]=r2[1]=r2[2]=r2[3]=0.f; }
  if (l >= 2) ld4b(bp - 2 * ZX_LD, r1); else { r1[0]=r1[1]=r1[2]=r1[3]=0.f; }
  if (l >= 3) ld4b(bp - 3 * ZX_LD, r0); else { r0[0]=r0[1]=r0[2]=r0[3]=0.f; }
  const int ch = col0 - 2048;
  ld4(cb + ch, bb);
#pragma unroll
  for (int j = 0; j < 4; ++j) {
    float w4[4]; ld4(cw + (ch + j) * 4, w4);
    float a = bb[j];
    a = fmaf(w4[0], r0[j], a);
    a = fmaf(w4[1], r1[j], a);
    a = fmaf(w4[2], r2[j], a);
    a = fmaf(w4[3], r3[j], a);
    outv[j] = a / (1.f + __expf(-a));
  }
}

// ---------------- pass A: per-chunk local state via MFMA (f16 operands) ------
__launch_bounds__(256, 2)
__global__ void passA_ssd(const ushort* __restrict__ zx,
                          const float* __restrict__ dtb,
                          const float* __restrict__ cw, const float* __restrict__ cb,
                          const float* __restrict__ dt_bias,
                          const float* __restrict__ A_log,
                          float* __restrict__ Sc, float* __restrict__ Pc,
                          float* __restrict__ xconv, float* __restrict__ bconv) {
  const int blk = blockIdx.x;
  const int c   = blk & (NCHUNK - 1);
  const int h   = blk >> 5;
  const int l0  = c * LCHUNK;
  const int t   = threadIdx.x;
  const int wave = t >> 6, lane = t & 63;
  const int ml = lane & 15, g4 = lane >> 4;
  const float Ah = -expf(A_log[h]);

  __shared__ float cum[LCHUNK];
  __shared__ float carry;
  __shared__ ushort Xt[LCHUNK * 40];
  __shared__ ushort Bt[D_STATE * 40];

  {
    float v = 0.f;
    if (t < LCHUNK) {
      float xv = dtb[(size_t)(l0 + t) * NHEADS + h] + dt_bias[h];
      float sp = (xv > 20.f) ? xv : log1pf(expf(xv));
      v = sp * Ah;
    }
    cum_scan(cum, v, t, &carry);
  }
  const float cend = cum[LCHUNK - 1];

  f32x4 acc[2][4];
#pragma unroll
  for (int i = 0; i < 2; ++i)
#pragma unroll
    for (int j = 0; j < 4; ++j) acc[i][j] = (f32x4){0.f, 0.f, 0.f, 0.f};
  const int p0 = wave * 32;

  for (int slab = 0; slab < 4; ++slab) {
    __syncthreads();
    for (int i = 0; i < 4; ++i) {
      int q = t + i * 256;
      int s = q >> 5, p4 = (q & 31) * 4;
      int l = l0 + slab * 32 + s;
      float xv[4];
      conv4b(zx, cw, cb, l, 2048 + h * HEADDIM + p4, xv);
      *(float4*)(xconv + (size_t)l * D_INNER + h * HEADDIM + p4) =
          make_float4(xv[0], xv[1], xv[2], xv[3]);
#pragma unroll
      for (int j = 0; j < 4; ++j) Xt[(p4 + j) * 40 + s] = f2h(xv[j]);
    }
    for (int i = 0; i < 2; ++i) {
      int q = t + i * 256;
      int s = q >> 4, n4 = (q & 15) * 4;
      int l = l0 + slab * 32 + s;
      float wd = __expf(cend - cum[slab * 32 + s]);
      float bv[4];
      conv4b(zx, cw, cb, l, 4096 + n4, bv);
      if (h == 0)
        *(float4*)(bconv + (size_t)l * D_STATE + n4) =
            make_float4(bv[0], bv[1], bv[2], bv[3]);
#pragma unroll
      for (int j = 0; j < 4; ++j) Bt[(n4 + j) * 40 + s] = f2h(bv[j] * wd);
    }
    __syncthreads();

    half8 xa[2];
#pragma unroll
    for (int pi = 0; pi < 2; ++pi)
      xa[pi] = *(const half8*)&Xt[(p0 + pi * 16 + ml) * 40 + g4 * 8];
#pragma unroll
    for (int ni = 0; ni < 4; ++ni) {
      half8 bh = *(const half8*)&Bt[(ni * 16 + ml) * 40 + g4 * 8];
#pragma unroll
      for (int pi = 0; pi < 2; ++pi)
        acc[pi][ni] = __builtin_amdgcn_mfma_f32_16x16x32_f16(xa[pi], bh, acc[pi][ni], 0, 0, 0);
    }
  }

  float* S = Sc + (size_t)blk * (HEADDIM * D_STATE);
#pragma unroll
  for (int pi = 0; pi < 2; ++pi)
#pragma unroll
    for (int ni = 0; ni < 4; ++ni) {
      int n = ni * 16 + ml;
#pragma unroll
      for (int r = 0; r < 4; ++r) {
        int p = p0 + pi * 16 + g4 * 4 + r;
        S[(size_t)p * D_STATE + n] = acc[pi][ni][r];
      }
    }
  if (t == 0) Pc[blk] = __expf(cend);
}

// ---------------- pass B: exclusive prefix over chunks ----------------
__global__ void scan_passB(float* __restrict__ Sc, const float* __restrict__ Pc) {
  const int h = blockIdx.x;
  const int e = blockIdx.y * 512 + threadIdx.x;
  const size_t hb = (size_t)h * NCHUNK;
  float st = 0.f;
  for (int c = 0; c < NCHUNK; ++c) {
    size_t idx = (hb + c) * (HEADDIM * D_STATE) + e;
    float P = Pc[hb + c];
    float v = Sc[idx];
    Sc[idx] = st;
    st = fmaf(P, st, v);
  }
}

// ---------------- pass C: intra-chunk attention + inter-chunk term (f16) -----
// LDS carve (12800 ushorts = 25.6KB):
//   [0,1280) Bsl0  [1280,2560) Bsl1  [2560,7680) Msl  [7680,12800) Xt
__launch_bounds__(256, 2)
__global__ void passC_ssd(const ushort* __restrict__ zx,
                          const float* __restrict__ dtb,
                          const float* __restrict__ cw, const float* __restrict__ cb,
                          const float* __restrict__ dt_bias,
                          const float* __restrict__ A_log,
                          const float* __restrict__ Dp,
                          const float* __restrict__ Sc,
                          const float* __restrict__ bconv,
                          float* __restrict__ ybuf) {
  const int blk = blockIdx.x;
  const int c   = blk & (NCHUNK - 1);
  const int h   = blk >> 5;
  const int l0  = c * LCHUNK;
  const int t   = threadIdx.x;
  const int wave = t >> 6, lane = t & 63;
  const int ml = lane & 15, g4 = lane >> 4;
  const int t0 = wave * 32;
  const float Ah = -expf(A_log[h]);
  const float Dh = Dp[h];

  __shared__ float cum[LCHUNK];
  __shared__ float carry;
  __shared__ ushort ldsb[12800];
  ushort* Bsl0 = ldsb;
  ushort* Bsl1 = ldsb + 1280;
  ushort* Msl  = ldsb + 2560;
  ushort* Xt   = ldsb + 7680;

  {
    float v = 0.f;
    if (t < LCHUNK) {
      float xv = dtb[(size_t)(l0 + t) * NHEADS + h] + dt_bias[h];
      float sp = (xv > 20.f) ? xv : log1pf(expf(xv));
      v = sp * Ah;
    }
    cum_scan(cum, v, t, &carry);
  }

  // ---- C conv -> swizzled scratch (ldsb[0,8192)), then f16 register frags --
  half8 cf[2][2];
  {
    ushort* CS = ldsb;
    int row = t >> 1, half_ = t & 1;
    int l = l0 + row;
    int colbase = 4160 + half_ * 32;
#pragma unroll
    for (int j0 = 0; j0 < 32; j0 += 4) {
      float cv[4];
      conv4b(zx, cw, cb, l, colbase + j0, cv);
      int colc = half_ * 32 + j0;
      int quad = colc >> 3;
      int addr = row * 64 + ((quad ^ (row & 7)) << 3) + (colc & 7);
      *(ushort4*)&CS[addr] = make_ushort4(f2h(cv[0]), f2h(cv[1]), f2h(cv[2]), f2h(cv[3]));
    }
    __syncthreads();
#pragma unroll
    for (int ks = 0; ks < 2; ++ks)
#pragma unroll
      for (int ti = 0; ti < 2; ++ti) {
        int rw = t0 + ti * 16 + ml;
        int ad = rw * 64 + (((ks * 4 + g4) ^ (rw & 7)) << 3);
        cf[ks][ti] = *(const half8*)&CS[ad];
      }
  }

  f32x4 accY[2][8];
#pragma unroll
  for (int i = 0; i < 2; ++i)
#pragma unroll
    for (int j = 0; j < 8; ++j) accY[i][j] = (f32x4){0.f, 0.f, 0.f, 0.f};

  const float* xcv = ybuf;   // materialized conv'd X (in-place region)

  // ---- intra-chunk: 4 s-slabs ----
  for (int slab = 0; slab < 4; ++slab) {
    __syncthreads();   // staging overwrite vs previous phase reads / C-scratch
#pragma unroll
    for (int i = 0; i < 2; ++i) {
      int q = t + i * 256;
      int s = q >> 4, n4 = (q & 15) * 4;
      int l = l0 + slab * 32 + s;
      float4 v = *(const float4*)(bconv + (size_t)l * D_STATE + n4);
      ushort* B = (n4 < 32) ? Bsl0 : Bsl1;
      int jj = n4 & 31;
      *(ushort4*)&B[s * 40 + jj] = make_ushort4(f2h(v.x), f2h(v.y), f2h(v.z), f2h(v.w));
    }
#pragma unroll
    for (int i = 0; i < 4; ++i) {
      int q = t + i * 256;
      int p = q & 127, sg = q >> 7;
      ushort hh[4];
#pragma unroll
      for (int j = 0; j < 4; ++j) {
        int l = l0 + slab * 32 + sg * 4 + j;
        hh[j] = f2h(xcv[(size_t)l * D_INNER + h * HEADDIM + p]);
      }
      *(ushort4*)&Xt[p * 40 + sg * 4] = make_ushort4(hh[0], hh[1], hh[2], hh[3]);
    }
    __syncthreads();

    if (wave >= slab) {        // slabs > wave are exactly zero after the mask
      f32x4 g[2][2];
#pragma unroll
      for (int i = 0; i < 2; ++i)
#pragma unroll
        for (int j = 0; j < 2; ++j) g[i][j] = (f32x4){0.f, 0.f, 0.f, 0.f};
#pragma unroll
      for (int ks = 0; ks < 2; ++ks) {
        const ushort* B = ks ? Bsl1 : Bsl0;
#pragma unroll
        for (int si = 0; si < 2; ++si) {
          half8 bh = *(const half8*)&B[(si * 16 + ml) * 40 + g4 * 8];
#pragma unroll
          for (int ti = 0; ti < 2; ++ti)
            g[ti][si] = __builtin_amdgcn_mfma_f32_16x16x32_f16(cf[ks][ti], bh, g[ti][si], 0, 0, 0);
        }
      }
#pragma unroll
      for (int ti = 0; ti < 2; ++ti)
#pragma unroll
        for (int si = 0; si < 2; ++si) {
          int sl = si * 16 + ml;
          int sg = slab * 32 + sl;
#pragma unroll
          for (int r = 0; r < 4; ++r) {
            int tg = t0 + ti * 16 + g4 * 4 + r;
            float coeff = (sg <= tg) ? __expf(cum[tg] - cum[sg]) : 0.f;
            float val = g[ti][si][r] * coeff + ((sg == tg) ? Dh : 0.f);
            Msl[tg * 40 + sl] = f2h(val);
          }
        }
      asm volatile("s_waitcnt lgkmcnt(0)" ::: "memory");
      half8 ma[2];
#pragma unroll
      for (int ti = 0; ti < 2; ++ti)
        ma[ti] = *(const half8*)&Msl[(t0 + ti * 16 + ml) * 40 + g4 * 8];
#pragma unroll
      for (int pi = 0; pi < 8; ++pi) {
        half8 xh = *(const half8*)&Xt[(pi * 16 + ml) * 40 + g4 * 8];
#pragma unroll
        for (int ti = 0; ti < 2; ++ti)
          accY[ti][pi] = __builtin_amdgcn_mfma_f32_16x16x32_f16(ma[ti], xh, accY[ti][pi], 0, 0, 0);
      }
    }
  }

  // ---- inter-chunk: Y += diag(exp(cum)) C . S_init ----
  const float* S = Sc + (size_t)blk * (HEADDIM * D_STATE);
#pragma unroll
  for (int ns = 0; ns < 2; ++ns) {
    __syncthreads();
#pragma unroll
    for (int i = 0; i < 4; ++i) {
      int q = t + i * 256;
      int p = q >> 3, j4 = (q & 7) * 4;
      float4 v = *(const float4*)(S + (size_t)p * D_STATE + ns * 32 + j4);
      *(ushort4*)&Xt[p * 40 + j4] = make_ushort4(f2h(v.x), f2h(v.y), f2h(v.z), f2h(v.w));
    }
    __syncthreads();
    half8 ma[2];
#pragma unroll
    for (int ti = 0; ti < 2; ++ti) {
      float e = __expf(cum[t0 + ti * 16 + ml]);
#pragma unroll
      for (int j = 0; j < 8; ++j)
        ma[ti][j] = (_Float16)((float)cf[ns][ti][j] * e);
    }
#pragma unroll
    for (int pi = 0; pi < 8; ++pi) {
      half8 xh = *(const half8*)&Xt[(pi * 16 + ml) * 40 + g4 * 8];
#pragma unroll
      for (int ti = 0; ti < 2; ++ti)
        accY[ti][pi] = __builtin_amdgcn_mfma_f32_16x16x32_f16(ma[ti], xh, accY[ti][pi], 0, 0, 0);
    }
  }

  // ---- epilogue: y = accY (overwrites this block's xconv tile) ----
#pragma unroll
  for (int ti = 0; ti < 2; ++ti)
#pragma unroll
    for (int pi = 0; pi < 8; ++pi) {
      int p = pi * 16 + ml;
#pragma unroll
      for (int r = 0; r < 4; ++r) {
        int l = l0 + t0 + ti * 16 + g4 * 4 + r;
        ybuf[(size_t)l * D_INNER + h * HEADDIM + p] = accY[ti][pi][r];
      }
    }
}

// ------- RMSNorm + sigmoid(z) gate, emits gated y as FP16 (feeds f16 GEMM) ---
__launch_bounds__(256)
__global__ void rmsnorm_gate_split(const float* __restrict__ ybuf,
                                   const ushort* __restrict__ zx,
                                   const float* __restrict__ rms_w,
                                   ushort* __restrict__ yh) {
  const int row = blockIdx.x;
  const int t   = threadIdx.x;
  const float* y  = ybuf + (size_t)row * D_INNER;
  const ushort* z = zx   + (size_t)row * ZX_LD;      // z cols [0,2048)

  float4 a  = *(const float4*)(y + t * 8);
  float4 bq = *(const float4*)(y + t * 8 + 4);
  float ss = a.x * a.x + a.y * a.y + a.z * a.z + a.w * a.w +
             bq.x * bq.x + bq.y * bq.y + bq.z * bq.z + bq.w * bq.w;
#pragma unroll
  for (int off = 32; off > 0; off >>= 1) ss += __shfl_down(ss, off);
  __shared__ float red[4];
  if ((t & 63) == 0) red[t >> 6] = ss;
  __syncthreads();
  float tot = red[0] + red[1] + red[2] + red[3];
  float scale = rsqrtf(tot * (1.f / (float)D_INNER) + RMS_EPS);

  float vy[8] = {a.x, a.y, a.z, a.w, bq.x, bq.y, bq.z, bq.w};
  ushort4 zv0 = *(const ushort4*)(z + t * 8);
  ushort4 zv1 = *(const ushort4*)(z + t * 8 + 4);
  ushort zz[8] = {zv0.x, zv0.y, zv0.z, zv0.w, zv1.x, zv1.y, zv1.z, zv1.w};
  ushort hh[8];
#pragma unroll
  for (int jj = 0; jj < 8; ++jj) {
    int col = t * 8 + jj;
    float g = 1.f / (1.f + __expf(-bf2f(zz[jj])));
    float v = vy[jj] * scale * rms_w[col] * g;
    hh[jj] = f2h(v);
  }
  size_t o = (size_t)row * D_INNER + t * 8;
  *(ushort4*)(yh + o)     = make_ushort4(hh[0], hh[1], hh[2], hh[3]);
  *(ushort4*)(yh + o + 4) = make_ushort4(hh[4], hh[5], hh[6], hh[7]);
}

// ---------------- launch ----------------
// ws layout identical (129.8 MB). f16 planes overwrite unused bf16 regions:
// w1f16 = w1h rows [0,4224) (dt rows preserved), w2f16 = w2h, uf16 = ybuf
// overlay (dead until passA).
extern "C" void kernel_launch(void* const* d_in, const int* in_sizes, int n_in,
                              void* d_out, int out_size, void* d_ws, size_t ws_size,
                              hipStream_t stream) {
  const float* u         = (const float*)d_in[0];
  const float* in_proj_w = (const float*)d_in[1];
  const float* conv_w    = (const float*)d_in[2];
  const float* conv_b    = (const float*)d_in[3];
  const float* dt_bias   = (const float*)d_in[4];
  const float* A_log     = (const float*)d_in[5];
  const float* Dp        = (const float*)d_in[6];
  const float* rms_w     = (const float*)d_in[7];
  const float* out_w     = (const float*)d_in[8];
  float* out = (float*)d_out;

  float* ws    = (float*)d_ws;
  ushort* zxbc = (ushort*)ws;                                  // [4096, 4224] bf16
  float* dtb   = ws   + (size_t)SEQLEN * ZX_LD / 2;            // [4096, 16]
  float* dtp   = dtb  + (size_t)SEQLEN * NHEADS;               // [8, 4096, 16]
  float* ybuf  = dtp  + (size_t)8 * SEQLEN * NHEADS;           // [4096, 2048]
  float* Pc    = ybuf + (size_t)SEQLEN * D_INNER;              // [512]
  float* Sc    = Pc   + 512;                                   // [512, 8192]
  ushort* uh   = (ushort*)(Sc + (size_t)NHEADS * NCHUNK * HEADDIM * D_STATE);
  ushort* ul   = uh  + (size_t)SEQLEN * D_MODEL;
  ushort* w1h  = ul  + (size_t)SEQLEN * D_MODEL;
  ushort* w1l  = w1h + (size_t)D_IN_PROJ * D_MODEL;
  ushort* w2h  = w1l + (size_t)D_IN_PROJ * D_MODEL;
  ushort* w2l  = w2h + (size_t)D_MODEL * D_INNER;
  ushort* yh   = (ushort*)Sc;                                  // overlay Sc (dead)
  float* Opart = ybuf;                                         // overlay ybuf (dead)
  float* bconv = dtp;                                          // overlay dtp (dead)
  ushort* uf16 = (ushort*)ybuf;                                // overlay ybuf (pre-passA)

  // weight conversions (once per call): bf16 hi/lo for dt rows, f16 elsewhere
  {
    int n4 = D_IN_PROJ * D_MODEL / 4;
    cvt_split<<<(n4 + 255) / 256, 256, 0, stream>>>(in_proj_w, w1h, w1l, n4);
    int z4 = ZX_LD * D_MODEL / 4;     // overwrite rows [0,4224) of w1h with f16
    cvt_f16<<<(z4 + 255) / 256, 256, 0, stream>>>(in_proj_w, w1h, z4);
    int m4 = D_MODEL * D_INNER / 4;
    cvt_f16<<<(m4 + 255) / 256, 256, 0, stream>>>(out_w, w2h, m4);
  }

  for (int b = 0; b < BATCH; ++b) {
    const float* u_b  = u   + (size_t)b * SEQLEN * D_MODEL;
    float*      out_b = out + (size_t)b * SEQLEN * D_MODEL;

    // 0) u_b -> bf16 hi/lo + f16 plane in ONE pass (u read once)
    {
      int n4 = SEQLEN * D_MODEL / 4;
      cvt_u3<<<(n4 + 255) / 256, 256, 0, stream>>>(u_b, uh, ul, uf16, n4);
    }

    // 1) merged z|x|B|C GEMM — f16, single-buffered 128^2 @ 5 blocks/CU
    //    (grid 40x32 = 1280 = 5x256 CUs exact; 5x32KB = 160KB LDS exact).
    {
      dim3 g(40, SEQLEN / 128, 1);
      gemm_f16<128, 64, true, false><<<g, 256, 0, stream>>>(uf16, w1h, (float*)zxbc,
                                                            ZX_LD, SEQLEN, ZX_LD,
                                                            D_MODEL, D_MODEL);
    }
    // 1b) dt GEMM (3-term bf16, split-K=8): N=16, near-fp32 (feeds exponentials)
    {
      const ushort* bh = w1h + (size_t)ZX_LD * D_MODEL;
      const ushort* bl = w1l + (size_t)ZX_LD * D_MODEL;
      dim3 g(1, SEQLEN / 128, 8);
      gemm_bf16p<128, 32, true, false><<<g, 256, 0, stream>>>(uh, ul, bh, bl,
                                                          dtp, NHEADS, SEQLEN, NHEADS,
                                                          D_MODEL, D_MODEL / 8, 0);
      add_dt<<<(SEQLEN * NHEADS / 4 + 255) / 256, 256, 0, stream>>>(dtp, dtb);
    }

    // 2-4) SSD chunked scan on MFMA (f16 scan operands)
    passA_ssd<<<NHEADS * NCHUNK, 256, 0, stream>>>(zxbc, dtb, conv_w, conv_b,
                                                   dt_bias, A_log, Sc, Pc,
                                                   ybuf, bconv);
    scan_passB<<<dim3(NHEADS, (HEADDIM * D_STATE) / 512), 512, 0, stream>>>(Sc, Pc);
    passC_ssd<<<NHEADS * NCHUNK, 256, 0, stream>>>(zxbc, dtb, conv_w, conv_b,
                                                   dt_bias, A_log, Dp, Sc,
                                                   bconv, ybuf);

    // 5) RMSNorm + gate -> y f16 (overlays Sc, dead now)
    rmsnorm_gate_split<<<SEQLEN, 256, 0, stream>>>(ybuf, zxbc, rms_w, yh);

    // 6) out GEMM, split-K=2 (512 blocks = 2/CU): depth-2 pipelined (R8-verified
    //    config; R9's no-split-K at 1 block/CU regressed ~+10us, reverted).
    {
      dim3 g(D_MODEL / 128, SEQLEN / 128, 2);
      gemm_f16<128, 64, false, true><<<g, 256, 0, stream>>>(yh, w2h, Opart, D_MODEL,
                                                            SEQLEN, D_MODEL,
                                                            D_INNER, D_INNER / 2);
    }
    // 7) combine partials -> out_b
    add_out<<<(SEQLEN * D_MODEL / 4 + 255) / 256, 256, 0, stream>>>(Opart, out_b,
                                                                    SEQLEN * D_MODEL / 4);
  }
}

// Round 11
// 464.311 us; speedup vs baseline: 1.1682x; 1.1682x over previous
//
#include <hip/hip_runtime.h>
#include <math.h>

// ---------------- problem constants ----------------
#define D_MODEL   1024
#define D_INNER   2048
#define D_STATE   64
#define HEADDIM   128
#define NHEADS    16
#define D_CONV    4
#define BATCH     2
#define SEQLEN    4096
#define RMS_EPS   1e-5f
#define D_IN_PROJ 4240

// zxbc buffer (bf16): cols [0,2048)=z, [2048,4096)=x, [4096,4160)=B, [4160,4224)=C
#define ZX_LD     4224

#define LCHUNK    128
#define NCHUNK    (SEQLEN / LCHUNK)   // 32

typedef __attribute__((ext_vector_type(8))) short short8;
typedef __attribute__((ext_vector_type(4))) float f32x4;
typedef _Float16 half8 __attribute__((ext_vector_type(8)));

__device__ __forceinline__ ushort f2bf(float f) {
  unsigned u = __float_as_uint(f);
  u += 0x7fff + ((u >> 16) & 1);          // RNE
  return (ushort)(u >> 16);
}
__device__ __forceinline__ float bf2f(ushort h) {
  return __uint_as_float(((unsigned)h) << 16);
}
__device__ __forceinline__ ushort f2h(float f) {
  _Float16 h = (_Float16)f;               // RNE
  ushort u; __builtin_memcpy(&u, &h, 2); return u;
}
__device__ __forceinline__ void ld4(const float* p, float* d) {
  float4 v = *(const float4*)p; d[0] = v.x; d[1] = v.y; d[2] = v.z; d[3] = v.w;
}
__device__ __forceinline__ void ld4b(const ushort* p, float* d) {
  ushort4 v = *(const ushort4*)p;
  d[0] = bf2f(v.x); d[1] = bf2f(v.y); d[2] = bf2f(v.z); d[3] = bf2f(v.w);
}

// async global->LDS, 16B per lane (global_load_lds_dwordx4)
__device__ __forceinline__ void gl_lds16(const ushort* g, ushort* l) {
  __builtin_amdgcn_global_load_lds(
      (const __attribute__((address_space(1))) unsigned int*)g,
      (__attribute__((address_space(3))) unsigned int*)l, 16, 0, 0);
}

// ---------------- split fp32 -> bf16 hi/lo planes (weights) ----------------
__global__ void cvt_split(const float* __restrict__ w,
                          ushort* __restrict__ hi, ushort* __restrict__ lo, int n4) {
  int i = blockIdx.x * 256 + threadIdx.x;
  if (i >= n4) return;
  float4 v = ((const float4*)w)[i];
  ushort h0 = f2bf(v.x), h1 = f2bf(v.y), h2 = f2bf(v.z), h3 = f2bf(v.w);
  ushort l0 = f2bf(v.x - bf2f(h0)), l1 = f2bf(v.y - bf2f(h1));
  ushort l2 = f2bf(v.z - bf2f(h2)), l3 = f2bf(v.w - bf2f(h3));
  ((ushort4*)hi)[i] = make_ushort4(h0, h1, h2, h3);
  ((ushort4*)lo)[i] = make_ushort4(l0, l1, l2, l3);
}

// ---------------- fp32 -> fp16 plane ----------------
__global__ void cvt_f16(const float* __restrict__ w, ushort* __restrict__ o, int n4) {
  int i = blockIdx.x * 256 + threadIdx.x;
  if (i >= n4) return;
  float4 v = ((const float4*)w)[i];
  ((ushort4*)o)[i] = make_ushort4(f2h(v.x), f2h(v.y), f2h(v.z), f2h(v.w));
}

// --------- u: one fp32 read -> bf16 hi/lo (dt GEMM) + f16 (in-proj) ---------
__global__ void cvt_u3(const float* __restrict__ w, ushort* __restrict__ hi,
                       ushort* __restrict__ lo, ushort* __restrict__ h16, int n4) {
  int i = blockIdx.x * 256 + threadIdx.x;
  if (i >= n4) return;
  float4 v = ((const float4*)w)[i];
  ushort h0 = f2bf(v.x), h1 = f2bf(v.y), h2 = f2bf(v.z), h3 = f2bf(v.w);
  ((ushort4*)hi)[i]  = make_ushort4(h0, h1, h2, h3);
  ((ushort4*)lo)[i]  = make_ushort4(f2bf(v.x - bf2f(h0)), f2bf(v.y - bf2f(h1)),
                                    f2bf(v.z - bf2f(h2)), f2bf(v.w - bf2f(h3)));
  ((ushort4*)h16)[i] = make_ushort4(f2h(v.x), f2h(v.y), f2h(v.z), f2h(v.w));
}

// ---------------- bf16-plane split NT GEMM (single-buffered; dt GEMM only) ---
template<int BM, int BK, bool ALO, bool OBF16>
__launch_bounds__(256, 3)
__global__ void gemm_bf16p(const ushort* __restrict__ Ah, const ushort* __restrict__ Al,
                           const ushort* __restrict__ Bh, const ushort* __restrict__ Bl,
                           float* __restrict__ C, int ldc,
                           int M, int N, int ldab, int Kslice, int n1term) {
  constexpr int BN = 128;
  constexpr int NQ = BK / 8;
  constexpr int RT = BM / 32;
  constexpr int CT = 4;
  constexpr int KS = BK / 32;

  __shared__ ushort As[ALO ? 2 : 1][BM * BK];
  __shared__ ushort Bs[2][BN * BK];

  const int bn   = blockIdx.x * BN;
  if (bn >= N) return;
  const bool two = (bn >= n1term);
  const int t    = threadIdx.x;
  const int bm   = blockIdx.y * BM;
  const int kz   = blockIdx.z;
  const int kb   = kz * Kslice;
  C += (size_t)kz * M * ldc;
  const int wave = t >> 6, lane = t & 63;
  const int ml   = lane & 15, g4 = lane >> 4;
  const int sw   = ml & (NQ - 1);
  const int wr   = wave & 1, wc = wave >> 1;
  const int r0   = wr * RT * 16, c0 = wc * CT * 16;

  f32x4 acc[RT][CT];
#pragma unroll
  for (int i = 0; i < RT; ++i)
#pragma unroll
    for (int j = 0; j < CT; ++j) acc[i][j] = (f32x4){0.f, 0.f, 0.f, 0.f};

  for (int k0 = kb; k0 < kb + Kslice; k0 += BK) {
    __syncthreads();
#pragma unroll
    for (int ii = 0; ii < BM * NQ / 256; ++ii) {
      int idx = t + ii * 256;
      int row = idx / NQ, qs = idx % NQ;
      int qg  = qs ^ (row & (NQ - 1));
      size_t go = (size_t)(bm + row) * ldab + k0 + qg * 8;
      gl_lds16(Ah + go, &As[0][idx * 8]);
      if (ALO) gl_lds16(Al + go, &As[ALO ? 1 : 0][idx * 8]);
    }
#pragma unroll
    for (int ii = 0; ii < BN * NQ / 256; ++ii) {
      int idx = t + ii * 256;
      int row = idx / NQ, qs = idx % NQ;
      int qg  = qs ^ (row & (NQ - 1));
      size_t go = (size_t)(bn + row) * ldab + k0 + qg * 8;
      gl_lds16(Bh + go, &Bs[0][idx * 8]);
      if (two) gl_lds16(Bl + go, &Bs[1][idx * 8]);
    }
    __syncthreads();

#pragma unroll
    for (int ks = 0; ks < KS; ++ks) {
      const int qA = ((ks * 4 + g4) ^ sw) * 8;
      short8 ah[RT], al[RT], bh[CT], bl[CT];
#pragma unroll
      for (int i = 0; i < RT; ++i) {
        int off = (r0 + i * 16 + ml) * BK + qA;
        ah[i] = *(const short8*)&As[0][off];
        if (ALO) al[i] = *(const short8*)&As[ALO ? 1 : 0][off];
      }
#pragma unroll
      for (int j = 0; j < CT; ++j) {
        int off = (c0 + j * 16 + ml) * BK + qA;
        bh[j] = *(const short8*)&Bs[0][off];
        if (two) bl[j] = *(const short8*)&Bs[1][off];
      }
#pragma unroll
      for (int i = 0; i < RT; ++i)
#pragma unroll
        for (int j = 0; j < CT; ++j) {
          acc[i][j] = __builtin_amdgcn_mfma_f32_16x16x32_bf16(ah[i], bh[j], acc[i][j], 0, 0, 0);
          if (two)
            acc[i][j] = __builtin_amdgcn_mfma_f32_16x16x32_bf16(ah[i], bl[j], acc[i][j], 0, 0, 0);
          if (ALO)
            acc[i][j] = __builtin_amdgcn_mfma_f32_16x16x32_bf16(al[i], bh[j], acc[i][j], 0, 0, 0);
        }
    }
  }

#pragma unroll
  for (int i = 0; i < RT; ++i)
#pragma unroll
    for (int j = 0; j < CT; ++j) {
      int col = bn + c0 + j * 16 + ml;
      if (col < N) {
        int rowb = bm + r0 + i * 16 + g4 * 4;
#pragma unroll
        for (int r = 0; r < 4; ++r) {
          if (OBF16) ((ushort*)C)[(size_t)(rowb + r) * ldc + col] = f2bf(acc[i][j][r]);
          else       C[(size_t)(rowb + r) * ldc + col] = acc[i][j][r];
        }
      }
    }
}

// ---------------- single-plane FP16 NT GEMM (128-col tiles) ----------------
// PIPE=false: single-buffered, 32KB LDS, __launch_bounds__(256,4): 4 blocks/CU.
// (R10 lesson: (256,5) forced VGPR 60->48, spilled acc to scratch — WRITE_SIZE
// 34->116MB, dur 50->97us. Occupancy bought with spills is a loss.)
// PIPE=true: depth-2 counted-vmcnt pipeline for 2-block/CU grid-limited sites.
template<int BM, int BK, bool OBF16, bool PIPE>
__launch_bounds__(256, PIPE ? 2 : 4)
__global__ void gemm_f16(const ushort* __restrict__ Ah, const ushort* __restrict__ Bh,
                         float* __restrict__ C, int ldc,
                         int M, int N, int ldab, int Kslice) {
  constexpr int BN = 128;
  constexpr int NQ = BK / 8;
  constexpr int RT = BM / 32;
  constexpr int CT = 4;
  constexpr int KS = BK / 32;
  constexpr int NBUF = PIPE ? 2 : 1;

  __shared__ ushort As[NBUF][BM * BK];
  __shared__ ushort Bs[NBUF][BN * BK];

  const int bn   = blockIdx.x * BN;
  if (bn >= N) return;                     // padded grid.x tiles exit
  const int t    = threadIdx.x;
  const int bm   = blockIdx.y * BM;
  const int kz   = blockIdx.z;
  const int kb   = kz * Kslice;
  C += (size_t)kz * M * ldc;
  const int wave = t >> 6, lane = t & 63;
  const int ml   = lane & 15, g4 = lane >> 4;
  const int sw   = ml & (NQ - 1);
  const int wr   = wave & 1, wc = wave >> 1;
  const int r0   = wr * RT * 16, c0 = wc * CT * 16;

  f32x4 acc[RT][CT];
#pragma unroll
  for (int i = 0; i < RT; ++i)
#pragma unroll
    for (int j = 0; j < CT; ++j) acc[i][j] = (f32x4){0.f, 0.f, 0.f, 0.f};

  auto stage = [&](int k0, int buf) {
#pragma unroll
    for (int ii = 0; ii < BM * NQ / 256; ++ii) {
      int idx = t + ii * 256;
      int row = idx / NQ, qs = idx % NQ;
      int qg  = qs ^ (row & (NQ - 1));
      size_t go = (size_t)(bm + row) * ldab + k0 + qg * 8;
      gl_lds16(Ah + go, &As[buf][idx * 8]);
    }
#pragma unroll
    for (int ii = 0; ii < BN * NQ / 256; ++ii) {
      int idx = t + ii * 256;
      int row = idx / NQ, qs = idx % NQ;
      int qg  = qs ^ (row & (NQ - 1));
      size_t go = (size_t)(bn + row) * ldab + k0 + qg * 8;   // rows past N read
      gl_lds16(Bh + go, &Bs[buf][idx * 8]);                  // adjacent valid memory
    }
  };

  auto compute = [&](int buf) {
#pragma unroll
    for (int ks = 0; ks < KS; ++ks) {
      const int qA = ((ks * 4 + g4) ^ sw) * 8;
      half8 ah[RT], bh[CT];
#pragma unroll
      for (int i = 0; i < RT; ++i)
        ah[i] = *(const half8*)&As[buf][(r0 + i * 16 + ml) * BK + qA];
#pragma unroll
      for (int j = 0; j < CT; ++j)
        bh[j] = *(const half8*)&Bs[buf][(c0 + j * 16 + ml) * BK + qA];
#pragma unroll
      for (int i = 0; i < RT; ++i)
#pragma unroll
        for (int j = 0; j < CT; ++j)
          acc[i][j] = __builtin_amdgcn_mfma_f32_16x16x32_f16(ah[i], bh[j], acc[i][j], 0, 0, 0);
    }
  };

  if (PIPE) {
    const int NIT = Kslice / BK;
    stage(kb, 0);
    if (NIT > 1) stage(kb + BK, 1);
    for (int it = 0; it < NIT; ++it) {
      const int buf = it & 1;
      if (it + 1 < NIT) asm volatile("s_waitcnt vmcnt(8)" ::: "memory");
      else              asm volatile("s_waitcnt vmcnt(0)" ::: "memory");
      __builtin_amdgcn_s_barrier();        // all waves' stage(it) landed
      __builtin_amdgcn_sched_barrier(0);
      compute(buf);
      __builtin_amdgcn_sched_barrier(0);
      __builtin_amdgcn_s_barrier();        // all waves done reading buf
      __builtin_amdgcn_sched_barrier(0);
      if (it + 2 < NIT) stage(kb + (it + 2) * BK, buf);
    }
  } else {
    for (int k0 = kb; k0 < kb + Kslice; k0 += BK) {
      __syncthreads();
      stage(k0, 0);
      __syncthreads();
      compute(0);
    }
  }

#pragma unroll
  for (int i = 0; i < RT; ++i)
#pragma unroll
    for (int j = 0; j < CT; ++j) {
      int col = bn + c0 + j * 16 + ml;
      if (col < N) {
        int rowb = bm + r0 + i * 16 + g4 * 4;
#pragma unroll
        for (int r = 0; r < 4; ++r) {
          if (OBF16) ((ushort*)C)[(size_t)(rowb + r) * ldc + col] = f2bf(acc[i][j][r]);
          else       C[(size_t)(rowb + r) * ldc + col] = acc[i][j][r];
        }
      }
    }
}

// ---------------- combine split-K partials: out = P0 + P1 ----------------
__global__ void add_out(const float* __restrict__ P, float* __restrict__ out, int n4) {
  int i = blockIdx.x * 256 + threadIdx.x;
  if (i >= n4) return;
  float4 a = ((const float4*)P)[i];
  float4 b = ((const float4*)(P + (size_t)SEQLEN * D_MODEL))[i];
  ((float4*)out)[i] = make_float4(a.x + b.x, a.y + b.y, a.z + b.z, a.w + b.w);
}

// ---------------- combine dt split-K=8 partials ----------------
__global__ void add_dt(const float* __restrict__ P, float* __restrict__ dtb) {
  int i = blockIdx.x * 256 + threadIdx.x;
  if (i >= SEQLEN * NHEADS / 4) return;
  float4 s = ((const float4*)P)[i];
#pragma unroll
  for (int k = 1; k < 8; ++k) {
    float4 v = ((const float4*)(P + (size_t)k * SEQLEN * NHEADS))[i];
    s.x += v.x; s.y += v.y; s.z += v.z; s.w += v.w;
  }
  ((float4*)dtb)[i] = s;
}

// =================== SSD chunked scan on MFMA ===================
// Scan operands are single-plane FP16 (2^-11 rel): inputs come from zxbc,
// already bf16 (2^-8 rel) — higher precision downstream is wasted (R8 verified).

__device__ __forceinline__ void cum_scan(float* cum, float v, int t, float* carry) {
  int lane = t & 63;
#pragma unroll
  for (int off = 1; off < 64; off <<= 1) {
    float o = __shfl_up(v, off);
    if (lane >= off) v += o;
  }
  if (t == 63) *carry = v;
  __syncthreads();
  if (t >= 64 && t < LCHUNK) v += *carry;
  if (t < LCHUNK) cum[t] = v;
  __syncthreads();
}

// conv+silu at (l, zxbc-col): channel = col - 2048; taps read bf16 rows above.
__device__ __forceinline__ void conv4b(const ushort* __restrict__ zx,
                                       const float* __restrict__ cw,
                                       const float* __restrict__ cb,
                                       int l, int col0, float* outv) {
  const ushort* bp = zx + (size_t)l * ZX_LD + col0;
  float r3[4], r2[4], r1[4], r0[4], bb[4];
  ld4b(bp, r3);
  if (l >= 1) ld4b(bp - ZX_LD, r2);     else { r2[0]=r2[1]=r2[2]=r2[3]=0.f; }
  if (l >= 2) ld4b(bp - 2 * ZX_LD, r1); else { r1[0]=r1[1]=r1[2]=r1[3]=0.f; }
  if (l >= 3) ld4b(bp - 3 * ZX_LD, r0); else { r0[0]=r0[1]=r0[2]=r0[3]=0.f; }
  const int ch = col0 - 2048;
  ld4(cb + ch, bb);
#pragma unroll
  for (int j = 0; j < 4; ++j) {
    float w4[4]; ld4(cw + (ch + j) * 4, w4);
    float a = bb[j];
    a = fmaf(w4[0], r0[j], a);
    a = fmaf(w4[1], r1[j], a);
    a = fmaf(w4[2], r2[j], a);
    a = fmaf(w4[3], r3[j], a);
    outv[j] = a / (1.f + __expf(-a));
  }
}

// ---------------- pass A: per-chunk local state via MFMA (f16 operands) ------
__launch_bounds__(256, 2)
__global__ void passA_ssd(const ushort* __restrict__ zx,
                          const float* __restrict__ dtb,
                          const float* __restrict__ cw, const float* __restrict__ cb,
                          const float* __restrict__ dt_bias,
                          const float* __restrict__ A_log,
                          float* __restrict__ Sc, float* __restrict__ Pc,
                          float* __restrict__ xconv, float* __restrict__ bconv) {
  const int blk = blockIdx.x;
  const int c   = blk & (NCHUNK - 1);
  const int h   = blk >> 5;
  const int l0  = c * LCHUNK;
  const int t   = threadIdx.x;
  const int wave = t >> 6, lane = t & 63;
  const int ml = lane & 15, g4 = lane >> 4;
  const float Ah = -expf(A_log[h]);

  __shared__ float cum[LCHUNK];
  __shared__ float carry;
  __shared__ ushort Xt[LCHUNK * 40];
  __shared__ ushort Bt[D_STATE * 40];

  {
    float v = 0.f;
    if (t < LCHUNK) {
      float xv = dtb[(size_t)(l0 + t) * NHEADS + h] + dt_bias[h];
      float sp = (xv > 20.f) ? xv : log1pf(expf(xv));
      v = sp * Ah;
    }
    cum_scan(cum, v, t, &carry);
  }
  const float cend = cum[LCHUNK - 1];

  f32x4 acc[2][4];
#pragma unroll
  for (int i = 0; i < 2; ++i)
#pragma unroll
    for (int j = 0; j < 4; ++j) acc[i][j] = (f32x4){0.f, 0.f, 0.f, 0.f};
  const int p0 = wave * 32;

  for (int slab = 0; slab < 4; ++slab) {
    __syncthreads();
    for (int i = 0; i < 4; ++i) {
      int q = t + i * 256;
      int s = q >> 5, p4 = (q & 31) * 4;
      int l = l0 + slab * 32 + s;
      float xv[4];
      conv4b(zx, cw, cb, l, 2048 + h * HEADDIM + p4, xv);
      *(float4*)(xconv + (size_t)l * D_INNER + h * HEADDIM + p4) =
          make_float4(xv[0], xv[1], xv[2], xv[3]);
#pragma unroll
      for (int j = 0; j < 4; ++j) Xt[(p4 + j) * 40 + s] = f2h(xv[j]);
    }
    for (int i = 0; i < 2; ++i) {
      int q = t + i * 256;
      int s = q >> 4, n4 = (q & 15) * 4;
      int l = l0 + slab * 32 + s;
      float wd = __expf(cend - cum[slab * 32 + s]);
      float bv[4];
      conv4b(zx, cw, cb, l, 4096 + n4, bv);
      if (h == 0)
        *(float4*)(bconv + (size_t)l * D_STATE + n4) =
            make_float4(bv[0], bv[1], bv[2], bv[3]);
#pragma unroll
      for (int j = 0; j < 4; ++j) Bt[(n4 + j) * 40 + s] = f2h(bv[j] * wd);
    }
    __syncthreads();

    half8 xa[2];
#pragma unroll
    for (int pi = 0; pi < 2; ++pi)
      xa[pi] = *(const half8*)&Xt[(p0 + pi * 16 + ml) * 40 + g4 * 8];
#pragma unroll
    for (int ni = 0; ni < 4; ++ni) {
      half8 bh = *(const half8*)&Bt[(ni * 16 + ml) * 40 + g4 * 8];
#pragma unroll
      for (int pi = 0; pi < 2; ++pi)
        acc[pi][ni] = __builtin_amdgcn_mfma_f32_16x16x32_f16(xa[pi], bh, acc[pi][ni], 0, 0, 0);
    }
  }

  float* S = Sc + (size_t)blk * (HEADDIM * D_STATE);
#pragma unroll
  for (int pi = 0; pi < 2; ++pi)
#pragma unroll
    for (int ni = 0; ni < 4; ++ni) {
      int n = ni * 16 + ml;
#pragma unroll
      for (int r = 0; r < 4; ++r) {
        int p = p0 + pi * 16 + g4 * 4 + r;
        S[(size_t)p * D_STATE + n] = acc[pi][ni][r];
      }
    }
  if (t == 0) Pc[blk] = __expf(cend);
}

// ---------------- pass B: exclusive prefix over chunks ----------------
__global__ void scan_passB(float* __restrict__ Sc, const float* __restrict__ Pc) {
  const int h = blockIdx.x;
  const int e = blockIdx.y * 512 + threadIdx.x;
  const size_t hb = (size_t)h * NCHUNK;
  float st = 0.f;
  for (int c = 0; c < NCHUNK; ++c) {
    size_t idx = (hb + c) * (HEADDIM * D_STATE) + e;
    float P = Pc[hb + c];
    float v = Sc[idx];
    Sc[idx] = st;
    st = fmaf(P, st, v);
  }
}

// ---------------- pass C: intra-chunk attention + inter-chunk term (f16) -----
// LDS carve (12800 ushorts = 25.6KB):
//   [0,1280) Bsl0  [1280,2560) Bsl1  [2560,7680) Msl  [7680,12800) Xt
__launch_bounds__(256, 2)
__global__ void passC_ssd(const ushort* __restrict__ zx,
                          const float* __restrict__ dtb,
                          const float* __restrict__ cw, const float* __restrict__ cb,
                          const float* __restrict__ dt_bias,
                          const float* __restrict__ A_log,
                          const float* __restrict__ Dp,
                          const float* __restrict__ Sc,
                          const float* __restrict__ bconv,
                          float* __restrict__ ybuf) {
  const int blk = blockIdx.x;
  const int c   = blk & (NCHUNK - 1);
  const int h   = blk >> 5;
  const int l0  = c * LCHUNK;
  const int t   = threadIdx.x;
  const int wave = t >> 6, lane = t & 63;
  const int ml = lane & 15, g4 = lane >> 4;
  const int t0 = wave * 32;
  const float Ah = -expf(A_log[h]);
  const float Dh = Dp[h];

  __shared__ float cum[LCHUNK];
  __shared__ float carry;
  __shared__ ushort ldsb[12800];
  ushort* Bsl0 = ldsb;
  ushort* Bsl1 = ldsb + 1280;
  ushort* Msl  = ldsb + 2560;
  ushort* Xt   = ldsb + 7680;

  {
    float v = 0.f;
    if (t < LCHUNK) {
      float xv = dtb[(size_t)(l0 + t) * NHEADS + h] + dt_bias[h];
      float sp = (xv > 20.f) ? xv : log1pf(expf(xv));
      v = sp * Ah;
    }
    cum_scan(cum, v, t, &carry);
  }

  // ---- C conv -> swizzled scratch (ldsb[0,8192)), then f16 register frags --
  half8 cf[2][2];
  {
    ushort* CS = ldsb;
    int row = t >> 1, half_ = t & 1;
    int l = l0 + row;
    int colbase = 4160 + half_ * 32;
#pragma unroll
    for (int j0 = 0; j0 < 32; j0 += 4) {
      float cv[4];
      conv4b(zx, cw, cb, l, colbase + j0, cv);
      int colc = half_ * 32 + j0;
      int quad = colc >> 3;
      int addr = row * 64 + ((quad ^ (row & 7)) << 3) + (colc & 7);
      *(ushort4*)&CS[addr] = make_ushort4(f2h(cv[0]), f2h(cv[1]), f2h(cv[2]), f2h(cv[3]));
    }
    __syncthreads();
#pragma unroll
    for (int ks = 0; ks < 2; ++ks)
#pragma unroll
      for (int ti = 0; ti < 2; ++ti) {
        int rw = t0 + ti * 16 + ml;
        int ad = rw * 64 + (((ks * 4 + g4) ^ (rw & 7)) << 3);
        cf[ks][ti] = *(const half8*)&CS[ad];
      }
  }

  f32x4 accY[2][8];
#pragma unroll
  for (int i = 0; i < 2; ++i)
#pragma unroll
    for (int j = 0; j < 8; ++j) accY[i][j] = (f32x4){0.f, 0.f, 0.f, 0.f};

  const float* xcv = ybuf;   // materialized conv'd X (in-place region)

  // ---- intra-chunk: 4 s-slabs ----
  for (int slab = 0; slab < 4; ++slab) {
    __syncthreads();   // staging overwrite vs previous phase reads / C-scratch
#pragma unroll
    for (int i = 0; i < 2; ++i) {
      int q = t + i * 256;
      int s = q >> 4, n4 = (q & 15) * 4;
      int l = l0 + slab * 32 + s;
      float4 v = *(const float4*)(bconv + (size_t)l * D_STATE + n4);
      ushort* B = (n4 < 32) ? Bsl0 : Bsl1;
      int jj = n4 & 31;
      *(ushort4*)&B[s * 40 + jj] = make_ushort4(f2h(v.x), f2h(v.y), f2h(v.z), f2h(v.w));
    }
#pragma unroll
    for (int i = 0; i < 4; ++i) {
      int q = t + i * 256;
      int p = q & 127, sg = q >> 7;
      ushort hh[4];
#pragma unroll
      for (int j = 0; j < 4; ++j) {
        int l = l0 + slab * 32 + sg * 4 + j;
        hh[j] = f2h(xcv[(size_t)l * D_INNER + h * HEADDIM + p]);
      }
      *(ushort4*)&Xt[p * 40 + sg * 4] = make_ushort4(hh[0], hh[1], hh[2], hh[3]);
    }
    __syncthreads();

    if (wave >= slab) {        // slabs > wave are exactly zero after the mask
      f32x4 g[2][2];
#pragma unroll
      for (int i = 0; i < 2; ++i)
#pragma unroll
        for (int j = 0; j < 2; ++j) g[i][j] = (f32x4){0.f, 0.f, 0.f, 0.f};
#pragma unroll
      for (int ks = 0; ks < 2; ++ks) {
        const ushort* B = ks ? Bsl1 : Bsl0;
#pragma unroll
        for (int si = 0; si < 2; ++si) {
          half8 bh = *(const half8*)&B[(si * 16 + ml) * 40 + g4 * 8];
#pragma unroll
          for (int ti = 0; ti < 2; ++ti)
            g[ti][si] = __builtin_amdgcn_mfma_f32_16x16x32_f16(cf[ks][ti], bh, g[ti][si], 0, 0, 0);
        }
      }
#pragma unroll
      for (int ti = 0; ti < 2; ++ti)
#pragma unroll
        for (int si = 0; si < 2; ++si) {
          int sl = si * 16 + ml;
          int sg = slab * 32 + sl;
#pragma unroll
          for (int r = 0; r < 4; ++r) {
            int tg = t0 + ti * 16 + g4 * 4 + r;
            float coeff = (sg <= tg) ? __expf(cum[tg] - cum[sg]) : 0.f;
            float val = g[ti][si][r] * coeff + ((sg == tg) ? Dh : 0.f);
            Msl[tg * 40 + sl] = f2h(val);
          }
        }
      asm volatile("s_waitcnt lgkmcnt(0)" ::: "memory");
      half8 ma[2];
#pragma unroll
      for (int ti = 0; ti < 2; ++ti)
        ma[ti] = *(const half8*)&Msl[(t0 + ti * 16 + ml) * 40 + g4 * 8];
#pragma unroll
      for (int pi = 0; pi < 8; ++pi) {
        half8 xh = *(const half8*)&Xt[(pi * 16 + ml) * 40 + g4 * 8];
#pragma unroll
        for (int ti = 0; ti < 2; ++ti)
          accY[ti][pi] = __builtin_amdgcn_mfma_f32_16x16x32_f16(ma[ti], xh, accY[ti][pi], 0, 0, 0);
      }
    }
  }

  // ---- inter-chunk: Y += diag(exp(cum)) C . S_init ----
  const float* S = Sc + (size_t)blk * (HEADDIM * D_STATE);
#pragma unroll
  for (int ns = 0; ns < 2; ++ns) {
    __syncthreads();
#pragma unroll
    for (int i = 0; i < 4; ++i) {
      int q = t + i * 256;
      int p = q >> 3, j4 = (q & 7) * 4;
      float4 v = *(const float4*)(S + (size_t)p * D_STATE + ns * 32 + j4);
      *(ushort4*)&Xt[p * 40 + j4] = make_ushort4(f2h(v.x), f2h(v.y), f2h(v.z), f2h(v.w));
    }
    __syncthreads();
    half8 ma[2];
#pragma unroll
    for (int ti = 0; ti < 2; ++ti) {
      float e = __expf(cum[t0 + ti * 16 + ml]);
#pragma unroll
      for (int j = 0; j < 8; ++j)
        ma[ti][j] = (_Float16)((float)cf[ns][ti][j] * e);
    }
#pragma unroll
    for (int pi = 0; pi < 8; ++pi) {
      half8 xh = *(const half8*)&Xt[(pi * 16 + ml) * 40 + g4 * 8];
#pragma unroll
      for (int ti = 0; ti < 2; ++ti)
        accY[ti][pi] = __builtin_amdgcn_mfma_f32_16x16x32_f16(ma[ti], xh, accY[ti][pi], 0, 0, 0);
    }
  }

  // ---- epilogue: y = accY (overwrites this block's xconv tile) ----
#pragma unroll
  for (int ti = 0; ti < 2; ++ti)
#pragma unroll
    for (int pi = 0; pi < 8; ++pi) {
      int p = pi * 16 + ml;
#pragma unroll
      for (int r = 0; r < 4; ++r) {
        int l = l0 + t0 + ti * 16 + g4 * 4 + r;
        ybuf[(size_t)l * D_INNER + h * HEADDIM + p] = accY[ti][pi][r];
      }
    }
}

// ------- RMSNorm + sigmoid(z) gate, emits gated y as FP16 (feeds f16 GEMM) ---
__launch_bounds__(256)
__global__ void rmsnorm_gate_split(const float* __restrict__ ybuf,
                                   const ushort* __restrict__ zx,
                                   const float* __restrict__ rms_w,
                                   ushort* __restrict__ yh) {
  const int row = blockIdx.x;
  const int t   = threadIdx.x;
  const float* y  = ybuf + (size_t)row * D_INNER;
  const ushort* z = zx   + (size_t)row * ZX_LD;      // z cols [0,2048)

  float4 a  = *(const float4*)(y + t * 8);
  float4 bq = *(const float4*)(y + t * 8 + 4);
  float ss = a.x * a.x + a.y * a.y + a.z * a.z + a.w * a.w +
             bq.x * bq.x + bq.y * bq.y + bq.z * bq.z + bq.w * bq.w;
#pragma unroll
  for (int off = 32; off > 0; off >>= 1) ss += __shfl_down(ss, off);
  __shared__ float red[4];
  if ((t & 63) == 0) red[t >> 6] = ss;
  __syncthreads();
  float tot = red[0] + red[1] + red[2] + red[3];
  float scale = rsqrtf(tot * (1.f / (float)D_INNER) + RMS_EPS);

  float vy[8] = {a.x, a.y, a.z, a.w, bq.x, bq.y, bq.z, bq.w};
  ushort4 zv0 = *(const ushort4*)(z + t * 8);
  ushort4 zv1 = *(const ushort4*)(z + t * 8 + 4);
  ushort zz[8] = {zv0.x, zv0.y, zv0.z, zv0.w, zv1.x, zv1.y, zv1.z, zv1.w};
  ushort hh[8];
#pragma unroll
  for (int jj = 0; jj < 8; ++jj) {
    int col = t * 8 + jj;
    float g = 1.f / (1.f + __expf(-bf2f(zz[jj])));
    float v = vy[jj] * scale * rms_w[col] * g;
    hh[jj] = f2h(v);
  }
  size_t o = (size_t)row * D_INNER + t * 8;
  *(ushort4*)(yh + o)     = make_ushort4(hh[0], hh[1], hh[2], hh[3]);
  *(ushort4*)(yh + o + 4) = make_ushort4(hh[4], hh[5], hh[6], hh[7]);
}

// ---------------- launch ----------------
// ws layout identical (129.8 MB). f16 planes overwrite unused bf16 regions:
// w1f16 = w1h rows [0,4224) (dt rows preserved), w2f16 = w2h, uf16 = ybuf
// overlay (dead until passA).
extern "C" void kernel_launch(void* const* d_in, const int* in_sizes, int n_in,
                              void* d_out, int out_size, void* d_ws, size_t ws_size,
                              hipStream_t stream) {
  const float* u         = (const float*)d_in[0];
  const float* in_proj_w = (const float*)d_in[1];
  const float* conv_w    = (const float*)d_in[2];
  const float* conv_b    = (const float*)d_in[3];
  const float* dt_bias   = (const float*)d_in[4];
  const float* A_log     = (const float*)d_in[5];
  const float* Dp        = (const float*)d_in[6];
  const float* rms_w     = (const float*)d_in[7];
  const float* out_w     = (const float*)d_in[8];
  float* out = (float*)d_out;

  float* ws    = (float*)d_ws;
  ushort* zxbc = (ushort*)ws;                                  // [4096, 4224] bf16
  float* dtb   = ws   + (size_t)SEQLEN * ZX_LD / 2;            // [4096, 16]
  float* dtp   = dtb  + (size_t)SEQLEN * NHEADS;               // [8, 4096, 16]
  float* ybuf  = dtp  + (size_t)8 * SEQLEN * NHEADS;           // [4096, 2048]
  float* Pc    = ybuf + (size_t)SEQLEN * D_INNER;              // [512]
  float* Sc    = Pc   + 512;                                   // [512, 8192]
  ushort* uh   = (ushort*)(Sc + (size_t)NHEADS * NCHUNK * HEADDIM * D_STATE);
  ushort* ul   = uh  + (size_t)SEQLEN * D_MODEL;
  ushort* w1h  = ul  + (size_t)SEQLEN * D_MODEL;
  ushort* w1l  = w1h + (size_t)D_IN_PROJ * D_MODEL;
  ushort* w2h  = w1l + (size_t)D_IN_PROJ * D_MODEL;
  ushort* w2l  = w2h + (size_t)D_MODEL * D_INNER;
  ushort* yh   = (ushort*)Sc;                                  // overlay Sc (dead)
  float* Opart = ybuf;                                         // overlay ybuf (dead)
  float* bconv = dtp;                                          // overlay dtp (dead)
  ushort* uf16 = (ushort*)ybuf;                                // overlay ybuf (pre-passA)

  // weight conversions (once per call): bf16 hi/lo for dt rows, f16 elsewhere
  {
    int n4 = D_IN_PROJ * D_MODEL / 4;
    cvt_split<<<(n4 + 255) / 256, 256, 0, stream>>>(in_proj_w, w1h, w1l, n4);
    int z4 = ZX_LD * D_MODEL / 4;     // overwrite rows [0,4224) of w1h with f16
    cvt_f16<<<(z4 + 255) / 256, 256, 0, stream>>>(in_proj_w, w1h, z4);
    int m4 = D_MODEL * D_INNER / 4;
    cvt_f16<<<(m4 + 255) / 256, 256, 0, stream>>>(out_w, w2h, m4);
  }

  for (int b = 0; b < BATCH; ++b) {
    const float* u_b  = u   + (size_t)b * SEQLEN * D_MODEL;
    float*      out_b = out + (size_t)b * SEQLEN * D_MODEL;

    // 0) u_b -> bf16 hi/lo + f16 plane in ONE pass (u read once)
    {
      int n4 = SEQLEN * D_MODEL / 4;
      cvt_u3<<<(n4 + 255) / 256, 256, 0, stream>>>(u_b, uh, ul, uf16, n4);
    }

    // 1) merged z|x|B|C GEMM — f16, single-buffered 128^2 @ 4 blocks/CU
    //    (R8-verified; R10's 5-block attempt spilled, reverted).
    {
      dim3 g(40, SEQLEN / 128, 1);
      gemm_f16<128, 64, true, false><<<g, 256, 0, stream>>>(uf16, w1h, (float*)zxbc,
                                                            ZX_LD, SEQLEN, ZX_LD,
                                                            D_MODEL, D_MODEL);
    }
    // 1b) dt GEMM (3-term bf16, split-K=8): N=16, near-fp32 (feeds exponentials)
    {
      const ushort* bh = w1h + (size_t)ZX_LD * D_MODEL;
      const ushort* bl = w1l + (size_t)ZX_LD * D_MODEL;
      dim3 g(1, SEQLEN / 128, 8);
      gemm_bf16p<128, 32, true, false><<<g, 256, 0, stream>>>(uh, ul, bh, bl,
                                                          dtp, NHEADS, SEQLEN, NHEADS,
                                                          D_MODEL, D_MODEL / 8, 0);
      add_dt<<<(SEQLEN * NHEADS / 4 + 255) / 256, 256, 0, stream>>>(dtp, dtb);
    }

    // 2-4) SSD chunked scan on MFMA (f16 scan operands)
    passA_ssd<<<NHEADS * NCHUNK, 256, 0, stream>>>(zxbc, dtb, conv_w, conv_b,
                                                   dt_bias, A_log, Sc, Pc,
                                                   ybuf, bconv);
    scan_passB<<<dim3(NHEADS, (HEADDIM * D_STATE) / 512), 512, 0, stream>>>(Sc, Pc);
    passC_ssd<<<NHEADS * NCHUNK, 256, 0, stream>>>(zxbc, dtb, conv_w, conv_b,
                                                   dt_bias, A_log, Dp, Sc,
                                                   bconv, ybuf);

    // 5) RMSNorm + gate -> y f16 (overlays Sc, dead now)
    rmsnorm_gate_split<<<SEQLEN, 256, 0, stream>>>(ybuf, zxbc, rms_w, yh);

    // 6) out GEMM, split-K=2 (512 blocks = 2/CU): depth-2 pipelined
    {
      dim3 g(D_MODEL / 128, SEQLEN / 128, 2);
      gemm_f16<128, 64, false, true><<<g, 256, 0, stream>>>(yh, w2h, Opart, D_MODEL,
                                                            SEQLEN, D_MODEL,
                                                            D_INNER, D_INNER / 2);
    }
    // 7) combine partials -> out_b
    add_out<<<(SEQLEN * D_MODEL / 4 + 255) / 256, 256, 0, stream>>>(Opart, out_b,
                                                                    SEQLEN * D_MODEL / 4);
  }
}

// Round 12
// 462.111 us; speedup vs baseline: 1.1737x; 1.0048x over previous
//
#include <hip/hip_runtime.h>
#include <math.h>

// ---------------- problem constants ----------------
#define D_MODEL   1024
#define D_INNER   2048
#define D_STATE   64
#define HEADDIM   128
#define NHEADS    16
#define D_CONV    4
#define BATCH     2
#define SEQLEN    4096
#define RMS_EPS   1e-5f
#define D_IN_PROJ 4240

// zxbc buffer (bf16): cols [0,2048)=z, [2048,4096)=x, [4096,4160)=B, [4160,4224)=C
#define ZX_LD     4224

#define LCHUNK    128
#define NCHUNK    (SEQLEN / LCHUNK)   // 32

typedef __attribute__((ext_vector_type(8))) short short8;
typedef __attribute__((ext_vector_type(4))) float f32x4;
typedef _Float16 half8 __attribute__((ext_vector_type(8)));

__device__ __forceinline__ ushort f2bf(float f) {
  unsigned u = __float_as_uint(f);
  u += 0x7fff + ((u >> 16) & 1);          // RNE
  return (ushort)(u >> 16);
}
__device__ __forceinline__ float bf2f(ushort h) {
  return __uint_as_float(((unsigned)h) << 16);
}
__device__ __forceinline__ ushort f2h(float f) {
  _Float16 h = (_Float16)f;               // RNE
  ushort u; __builtin_memcpy(&u, &h, 2); return u;
}
__device__ __forceinline__ void ld4(const float* p, float* d) {
  float4 v = *(const float4*)p; d[0] = v.x; d[1] = v.y; d[2] = v.z; d[3] = v.w;
}
__device__ __forceinline__ void ld4b(const ushort* p, float* d) {
  ushort4 v = *(const ushort4*)p;
  d[0] = bf2f(v.x); d[1] = bf2f(v.y); d[2] = bf2f(v.z); d[3] = bf2f(v.w);
}

// async global->LDS, 16B per lane (global_load_lds_dwordx4)
__device__ __forceinline__ void gl_lds16(const ushort* g, ushort* l) {
  __builtin_amdgcn_global_load_lds(
      (const __attribute__((address_space(1))) unsigned int*)g,
      (__attribute__((address_space(3))) unsigned int*)l, 16, 0, 0);
}

// ---------------- split fp32 -> bf16 hi/lo planes (weights) ----------------
__global__ void cvt_split(const float* __restrict__ w,
                          ushort* __restrict__ hi, ushort* __restrict__ lo, int n4) {
  int i = blockIdx.x * 256 + threadIdx.x;
  if (i >= n4) return;
  float4 v = ((const float4*)w)[i];
  ushort h0 = f2bf(v.x), h1 = f2bf(v.y), h2 = f2bf(v.z), h3 = f2bf(v.w);
  ushort l0 = f2bf(v.x - bf2f(h0)), l1 = f2bf(v.y - bf2f(h1));
  ushort l2 = f2bf(v.z - bf2f(h2)), l3 = f2bf(v.w - bf2f(h3));
  ((ushort4*)hi)[i] = make_ushort4(h0, h1, h2, h3);
  ((ushort4*)lo)[i] = make_ushort4(l0, l1, l2, l3);
}

// ---------------- fp32 -> fp16 plane ----------------
__global__ void cvt_f16(const float* __restrict__ w, ushort* __restrict__ o, int n4) {
  int i = blockIdx.x * 256 + threadIdx.x;
  if (i >= n4) return;
  float4 v = ((const float4*)w)[i];
  ((ushort4*)o)[i] = make_ushort4(f2h(v.x), f2h(v.y), f2h(v.z), f2h(v.w));
}

// --------- u: one fp32 read -> bf16 hi/lo (dt GEMM) + f16 (in-proj) ---------
__global__ void cvt_u3(const float* __restrict__ w, ushort* __restrict__ hi,
                       ushort* __restrict__ lo, ushort* __restrict__ h16, int n4) {
  int i = blockIdx.x * 256 + threadIdx.x;
  if (i >= n4) return;
  float4 v = ((const float4*)w)[i];
  ushort h0 = f2bf(v.x), h1 = f2bf(v.y), h2 = f2bf(v.z), h3 = f2bf(v.w);
  ((ushort4*)hi)[i]  = make_ushort4(h0, h1, h2, h3);
  ((ushort4*)lo)[i]  = make_ushort4(f2bf(v.x - bf2f(h0)), f2bf(v.y - bf2f(h1)),
                                    f2bf(v.z - bf2f(h2)), f2bf(v.w - bf2f(h3)));
  ((ushort4*)h16)[i] = make_ushort4(f2h(v.x), f2h(v.y), f2h(v.z), f2h(v.w));
}

// ---------------- bf16-plane split NT GEMM (single-buffered; dt GEMM only) ---
template<int BM, int BK, bool ALO, bool OBF16>
__launch_bounds__(256, 3)
__global__ void gemm_bf16p(const ushort* __restrict__ Ah, const ushort* __restrict__ Al,
                           const ushort* __restrict__ Bh, const ushort* __restrict__ Bl,
                           float* __restrict__ C, int ldc,
                           int M, int N, int ldab, int Kslice, int n1term) {
  constexpr int BN = 128;
  constexpr int NQ = BK / 8;
  constexpr int RT = BM / 32;
  constexpr int CT = 4;
  constexpr int KS = BK / 32;

  __shared__ ushort As[ALO ? 2 : 1][BM * BK];
  __shared__ ushort Bs[2][BN * BK];

  const int bn   = blockIdx.x * BN;
  if (bn >= N) return;
  const bool two = (bn >= n1term);
  const int t    = threadIdx.x;
  const int bm   = blockIdx.y * BM;
  const int kz   = blockIdx.z;
  const int kb   = kz * Kslice;
  C += (size_t)kz * M * ldc;
  const int wave = t >> 6, lane = t & 63;
  const int ml   = lane & 15, g4 = lane >> 4;
  const int sw   = ml & (NQ - 1);
  const int wr   = wave & 1, wc = wave >> 1;
  const int r0   = wr * RT * 16, c0 = wc * CT * 16;

  f32x4 acc[RT][CT];
#pragma unroll
  for (int i = 0; i < RT; ++i)
#pragma unroll
    for (int j = 0; j < CT; ++j) acc[i][j] = (f32x4){0.f, 0.f, 0.f, 0.f};

  for (int k0 = kb; k0 < kb + Kslice; k0 += BK) {
    __syncthreads();
#pragma unroll
    for (int ii = 0; ii < BM * NQ / 256; ++ii) {
      int idx = t + ii * 256;
      int row = idx / NQ, qs = idx % NQ;
      int qg  = qs ^ (row & (NQ - 1));
      size_t go = (size_t)(bm + row) * ldab + k0 + qg * 8;
      gl_lds16(Ah + go, &As[0][idx * 8]);
      if (ALO) gl_lds16(Al + go, &As[ALO ? 1 : 0][idx * 8]);
    }
#pragma unroll
    for (int ii = 0; ii < BN * NQ / 256; ++ii) {
      int idx = t + ii * 256;
      int row = idx / NQ, qs = idx % NQ;
      int qg  = qs ^ (row & (NQ - 1));
      size_t go = (size_t)(bn + row) * ldab + k0 + qg * 8;
      gl_lds16(Bh + go, &Bs[0][idx * 8]);
      if (two) gl_lds16(Bl + go, &Bs[1][idx * 8]);
    }
    __syncthreads();

#pragma unroll
    for (int ks = 0; ks < KS; ++ks) {
      const int qA = ((ks * 4 + g4) ^ sw) * 8;
      short8 ah[RT], al[RT], bh[CT], bl[CT];
#pragma unroll
      for (int i = 0; i < RT; ++i) {
        int off = (r0 + i * 16 + ml) * BK + qA;
        ah[i] = *(const short8*)&As[0][off];
        if (ALO) al[i] = *(const short8*)&As[ALO ? 1 : 0][off];
      }
#pragma unroll
      for (int j = 0; j < CT; ++j) {
        int off = (c0 + j * 16 + ml) * BK + qA;
        bh[j] = *(const short8*)&Bs[0][off];
        if (two) bl[j] = *(const short8*)&Bs[1][off];
      }
#pragma unroll
      for (int i = 0; i < RT; ++i)
#pragma unroll
        for (int j = 0; j < CT; ++j) {
          acc[i][j] = __builtin_amdgcn_mfma_f32_16x16x32_bf16(ah[i], bh[j], acc[i][j], 0, 0, 0);
          if (two)
            acc[i][j] = __builtin_amdgcn_mfma_f32_16x16x32_bf16(ah[i], bl[j], acc[i][j], 0, 0, 0);
          if (ALO)
            acc[i][j] = __builtin_amdgcn_mfma_f32_16x16x32_bf16(al[i], bh[j], acc[i][j], 0, 0, 0);
        }
    }
  }

#pragma unroll
  for (int i = 0; i < RT; ++i)
#pragma unroll
    for (int j = 0; j < CT; ++j) {
      int col = bn + c0 + j * 16 + ml;
      if (col < N) {
        int rowb = bm + r0 + i * 16 + g4 * 4;
#pragma unroll
        for (int r = 0; r < 4; ++r) {
          if (OBF16) ((ushort*)C)[(size_t)(rowb + r) * ldc + col] = f2bf(acc[i][j][r]);
          else       C[(size_t)(rowb + r) * ldc + col] = acc[i][j][r];
        }
      }
    }
}

// ---------------- single-plane FP16 NT GEMM (128-col tiles) ----------------
// PIPE=false: single-buffered, 32KB LDS, (256,4): 4 blocks/CU (R10: (256,5)
// spilled acc — occupancy bought with spills is a loss).
// PIPE=true: depth-2 counted-vmcnt pipeline for 2-block/CU grid-limited sites.
template<int BM, int BK, bool OBF16, bool PIPE>
__launch_bounds__(256, PIPE ? 2 : 4)
__global__ void gemm_f16(const ushort* __restrict__ Ah, const ushort* __restrict__ Bh,
                         float* __restrict__ C, int ldc,
                         int M, int N, int ldab, int Kslice) {
  constexpr int BN = 128;
  constexpr int NQ = BK / 8;
  constexpr int RT = BM / 32;
  constexpr int CT = 4;
  constexpr int KS = BK / 32;
  constexpr int NBUF = PIPE ? 2 : 1;

  __shared__ ushort As[NBUF][BM * BK];
  __shared__ ushort Bs[NBUF][BN * BK];

  const int bn   = blockIdx.x * BN;
  if (bn >= N) return;                     // padded grid.x tiles exit
  const int t    = threadIdx.x;
  const int bm   = blockIdx.y * BM;
  const int kz   = blockIdx.z;
  const int kb   = kz * Kslice;
  C += (size_t)kz * M * ldc;
  const int wave = t >> 6, lane = t & 63;
  const int ml   = lane & 15, g4 = lane >> 4;
  const int sw   = ml & (NQ - 1);
  const int wr   = wave & 1, wc = wave >> 1;
  const int r0   = wr * RT * 16, c0 = wc * CT * 16;

  f32x4 acc[RT][CT];
#pragma unroll
  for (int i = 0; i < RT; ++i)
#pragma unroll
    for (int j = 0; j < CT; ++j) acc[i][j] = (f32x4){0.f, 0.f, 0.f, 0.f};

  auto stage = [&](int k0, int buf) {
#pragma unroll
    for (int ii = 0; ii < BM * NQ / 256; ++ii) {
      int idx = t + ii * 256;
      int row = idx / NQ, qs = idx % NQ;
      int qg  = qs ^ (row & (NQ - 1));
      size_t go = (size_t)(bm + row) * ldab + k0 + qg * 8;
      gl_lds16(Ah + go, &As[buf][idx * 8]);
    }
#pragma unroll
    for (int ii = 0; ii < BN * NQ / 256; ++ii) {
      int idx = t + ii * 256;
      int row = idx / NQ, qs = idx % NQ;
      int qg  = qs ^ (row & (NQ - 1));
      size_t go = (size_t)(bn + row) * ldab + k0 + qg * 8;   // rows past N read
      gl_lds16(Bh + go, &Bs[buf][idx * 8]);                  // adjacent valid memory
    }
  };

  auto compute = [&](int buf) {
#pragma unroll
    for (int ks = 0; ks < KS; ++ks) {
      const int qA = ((ks * 4 + g4) ^ sw) * 8;
      half8 ah[RT], bh[CT];
#pragma unroll
      for (int i = 0; i < RT; ++i)
        ah[i] = *(const half8*)&As[buf][(r0 + i * 16 + ml) * BK + qA];
#pragma unroll
      for (int j = 0; j < CT; ++j)
        bh[j] = *(const half8*)&Bs[buf][(c0 + j * 16 + ml) * BK + qA];
#pragma unroll
      for (int i = 0; i < RT; ++i)
#pragma unroll
        for (int j = 0; j < CT; ++j)
          acc[i][j] = __builtin_amdgcn_mfma_f32_16x16x32_f16(ah[i], bh[j], acc[i][j], 0, 0, 0);
    }
  };

  if (PIPE) {
    const int NIT = Kslice / BK;
    stage(kb, 0);
    if (NIT > 1) stage(kb + BK, 1);
    for (int it = 0; it < NIT; ++it) {
      const int buf = it & 1;
      if (it + 1 < NIT) asm volatile("s_waitcnt vmcnt(8)" ::: "memory");
      else              asm volatile("s_waitcnt vmcnt(0)" ::: "memory");
      __builtin_amdgcn_s_barrier();        // all waves' stage(it) landed
      __builtin_amdgcn_sched_barrier(0);
      compute(buf);
      __builtin_amdgcn_sched_barrier(0);
      __builtin_amdgcn_s_barrier();        // all waves done reading buf
      __builtin_amdgcn_sched_barrier(0);
      if (it + 2 < NIT) stage(kb + (it + 2) * BK, buf);
    }
  } else {
    for (int k0 = kb; k0 < kb + Kslice; k0 += BK) {
      __syncthreads();
      stage(k0, 0);
      __syncthreads();
      compute(0);
    }
  }

#pragma unroll
  for (int i = 0; i < RT; ++i)
#pragma unroll
    for (int j = 0; j < CT; ++j) {
      int col = bn + c0 + j * 16 + ml;
      if (col < N) {
        int rowb = bm + r0 + i * 16 + g4 * 4;
#pragma unroll
        for (int r = 0; r < 4; ++r) {
          if (OBF16) ((ushort*)C)[(size_t)(rowb + r) * ldc + col] = f2bf(acc[i][j][r]);
          else       C[(size_t)(rowb + r) * ldc + col] = acc[i][j][r];
        }
      }
    }
}

// ---------------- combine split-K partials: out = P0 + P1 ----------------
__global__ void add_out(const float* __restrict__ P, float* __restrict__ out, int n4) {
  int i = blockIdx.x * 256 + threadIdx.x;
  if (i >= n4) return;
  float4 a = ((const float4*)P)[i];
  float4 b = ((const float4*)(P + (size_t)SEQLEN * D_MODEL))[i];
  ((float4*)out)[i] = make_float4(a.x + b.x, a.y + b.y, a.z + b.z, a.w + b.w);
}

// ---------------- combine dt split-K=8 partials ----------------
__global__ void add_dt(const float* __restrict__ P, float* __restrict__ dtb) {
  int i = blockIdx.x * 256 + threadIdx.x;
  if (i >= SEQLEN * NHEADS / 4) return;
  float4 s = ((const float4*)P)[i];
#pragma unroll
  for (int k = 1; k < 8; ++k) {
    float4 v = ((const float4*)(P + (size_t)k * SEQLEN * NHEADS))[i];
    s.x += v.x; s.y += v.y; s.z += v.z; s.w += v.w;
  }
  ((float4*)dtb)[i] = s;
}

// =================== SSD chunked scan on MFMA ===================
// R12: passA/passC split along p (HEADDIM 128 -> 2 halves, blockIdx.y).
// Grid 512 -> 1024 = 4 blocks/CU (was 2, grid-limited; R11 PMC: MfmaUtil
// 1.8%, VALUBusy 11%, HBM 13% — pure latency bound, needs TLP). p-independent
// work (cum, C-conv/phase1, B staging, mask) duplicated per half — cheap since
// all pipes idle. Per-element numerics bit-identical.

__device__ __forceinline__ void cum_scan(float* cum, float v, int t, float* carry) {
  int lane = t & 63;
#pragma unroll
  for (int off = 1; off < 64; off <<= 1) {
    float o = __shfl_up(v, off);
    if (lane >= off) v += o;
  }
  if (t == 63) *carry = v;
  __syncthreads();
  if (t >= 64 && t < LCHUNK) v += *carry;
  if (t < LCHUNK) cum[t] = v;
  __syncthreads();
}

// conv+silu at (l, zxbc-col): channel = col - 2048; taps read bf16 rows above.
__device__ __forceinline__ void conv4b(const ushort* __restrict__ zx,
                                       const float* __restrict__ cw,
                                       const float* __restrict__ cb,
                                       int l, int col0, float* outv) {
  const ushort* bp = zx + (size_t)l * ZX_LD + col0;
  float r3[4], r2[4], r1[4], r0[4], bb[4];
  ld4b(bp, r3);
  if (l >= 1) ld4b(bp - ZX_LD, r2);     else { r2[0]=r2[1]=r2[2]=r2[3]=0.f; }
  if (l >= 2) ld4b(bp - 2 * ZX_LD, r1); else { r1[0]=r1[1]=r1[2]=r1[3]=0.f; }
  if (l >= 3) ld4b(bp - 3 * ZX_LD, r0); else { r0[0]=r0[1]=r0[2]=r0[3]=0.f; }
  const int ch = col0 - 2048;
  ld4(cb + ch, bb);
#pragma unroll
  for (int j = 0; j < 4; ++j) {
    float w4[4]; ld4(cw + (ch + j) * 4, w4);
    float a = bb[j];
    a = fmaf(w4[0], r0[j], a);
    a = fmaf(w4[1], r1[j], a);
    a = fmaf(w4[2], r2[j], a);
    a = fmaf(w4[3], r3[j], a);
    outv[j] = a / (1.f + __expf(-a));
  }
}

// ---------------- pass A: per-chunk local state (f16, p-split x2) ------------
__launch_bounds__(256, 4)
__global__ void passA_ssd(const ushort* __restrict__ zx,
                          const float* __restrict__ dtb,
                          const float* __restrict__ cw, const float* __restrict__ cb,
                          const float* __restrict__ dt_bias,
                          const float* __restrict__ A_log,
                          float* __restrict__ Sc, float* __restrict__ Pc,
                          float* __restrict__ xconv, float* __restrict__ bconv) {
  const int blk = blockIdx.x;
  const int c   = blk & (NCHUNK - 1);
  const int h   = blk >> 5;
  const int ph  = blockIdx.y;           // p-half: p in [ph*64, ph*64+64)
  const int pbase = ph * 64;
  const int l0  = c * LCHUNK;
  const int t   = threadIdx.x;
  const int wave = t >> 6, lane = t & 63;
  const int ml = lane & 15, g4 = lane >> 4;
  const float Ah = -expf(A_log[h]);

  __shared__ float cum[LCHUNK];
  __shared__ float carry;
  __shared__ ushort Xt[64 * 40];
  __shared__ ushort Bt[D_STATE * 40];

  {
    float v = 0.f;
    if (t < LCHUNK) {
      float xv = dtb[(size_t)(l0 + t) * NHEADS + h] + dt_bias[h];
      float sp = (xv > 20.f) ? xv : log1pf(expf(xv));
      v = sp * Ah;
    }
    cum_scan(cum, v, t, &carry);
  }
  const float cend = cum[LCHUNK - 1];

  f32x4 acc[4];
#pragma unroll
  for (int j = 0; j < 4; ++j) acc[j] = (f32x4){0.f, 0.f, 0.f, 0.f};
  const int p0 = wave * 16;             // 4 waves x 16 = 64 local p rows

  for (int slab = 0; slab < 4; ++slab) {
    __syncthreads();
    // X conv for this p-half: 64 p x 32 s
    for (int i = 0; i < 2; ++i) {
      int q = t + i * 256;
      int s = q >> 4, p4 = (q & 15) * 4;
      int l = l0 + slab * 32 + s;
      float xv[4];
      conv4b(zx, cw, cb, l, 2048 + h * HEADDIM + pbase + p4, xv);
      *(float4*)(xconv + (size_t)l * D_INNER + h * HEADDIM + pbase + p4) =
          make_float4(xv[0], xv[1], xv[2], xv[3]);
#pragma unroll
      for (int j = 0; j < 4; ++j) Xt[(p4 + j) * 40 + s] = f2h(xv[j]);
    }
    // B conv (duplicated per half; bconv single-writer)
    for (int i = 0; i < 2; ++i) {
      int q = t + i * 256;
      int s = q >> 4, n4 = (q & 15) * 4;
      int l = l0 + slab * 32 + s;
      float wd = __expf(cend - cum[slab * 32 + s]);
      float bv[4];
      conv4b(zx, cw, cb, l, 4096 + n4, bv);
      if (h == 0 && ph == 0)
        *(float4*)(bconv + (size_t)l * D_STATE + n4) =
            make_float4(bv[0], bv[1], bv[2], bv[3]);
#pragma unroll
      for (int j = 0; j < 4; ++j) Bt[(n4 + j) * 40 + s] = f2h(bv[j] * wd);
    }
    __syncthreads();

    half8 xa = *(const half8*)&Xt[(p0 + ml) * 40 + g4 * 8];
#pragma unroll
    for (int ni = 0; ni < 4; ++ni) {
      half8 bh = *(const half8*)&Bt[(ni * 16 + ml) * 40 + g4 * 8];
      acc[ni] = __builtin_amdgcn_mfma_f32_16x16x32_f16(xa, bh, acc[ni], 0, 0, 0);
    }
  }

  float* S = Sc + (size_t)blk * (HEADDIM * D_STATE);
#pragma unroll
  for (int ni = 0; ni < 4; ++ni) {
    int n = ni * 16 + ml;
#pragma unroll
    for (int r = 0; r < 4; ++r) {
      int p = pbase + p0 + g4 * 4 + r;
      S[(size_t)p * D_STATE + n] = acc[ni][r];
    }
  }
  if (t == 0 && ph == 0) Pc[blk] = __expf(cend);
}

// ---------------- pass B: exclusive prefix over chunks ----------------
__global__ void scan_passB(float* __restrict__ Sc, const float* __restrict__ Pc) {
  const int h = blockIdx.x;
  const int e = blockIdx.y * 512 + threadIdx.x;
  const size_t hb = (size_t)h * NCHUNK;
  float st = 0.f;
  for (int c = 0; c < NCHUNK; ++c) {
    size_t idx = (hb + c) * (HEADDIM * D_STATE) + e;
    float P = Pc[hb + c];
    float v = Sc[idx];
    Sc[idx] = st;
    st = fmaf(P, st, v);
  }
}

// ---------------- pass C: intra-chunk attention (f16, p-split x2) ------------
// LDS carve (10240 ushorts = 20.5KB):
//   [0,1280) Bsl0  [1280,2560) Bsl1  [2560,7680) Msl(128x40)  [7680,10240) Xt(64x40)
// C-conv scratch at entry uses [0,8192) (dead then; slab entry barrier orders).
__launch_bounds__(256, 4)
__global__ void passC_ssd(const ushort* __restrict__ zx,
                          const float* __restrict__ dtb,
                          const float* __restrict__ cw, const float* __restrict__ cb,
                          const float* __restrict__ dt_bias,
                          const float* __restrict__ A_log,
                          const float* __restrict__ Dp,
                          const float* __restrict__ Sc,
                          const float* __restrict__ bconv,
                          float* __restrict__ ybuf) {
  const int blk = blockIdx.x;
  const int c   = blk & (NCHUNK - 1);
  const int h   = blk >> 5;
  const int ph  = blockIdx.y;           // p-half
  const int pbase = ph * 64;
  const int l0  = c * LCHUNK;
  const int t   = threadIdx.x;
  const int wave = t >> 6, lane = t & 63;
  const int ml = lane & 15, g4 = lane >> 4;
  const int t0 = wave * 32;
  const float Ah = -expf(A_log[h]);
  const float Dh = Dp[h];

  __shared__ float cum[LCHUNK];
  __shared__ float carry;
  __shared__ ushort ldsb[10240];
  ushort* Bsl0 = ldsb;
  ushort* Bsl1 = ldsb + 1280;
  ushort* Msl  = ldsb + 2560;
  ushort* Xt   = ldsb + 7680;

  {
    float v = 0.f;
    if (t < LCHUNK) {
      float xv = dtb[(size_t)(l0 + t) * NHEADS + h] + dt_bias[h];
      float sp = (xv > 20.f) ? xv : log1pf(expf(xv));
      v = sp * Ah;
    }
    cum_scan(cum, v, t, &carry);
  }

  // ---- C conv -> swizzled scratch (ldsb[0,8192)), then f16 register frags --
  half8 cf[2][2];
  {
    ushort* CS = ldsb;
    int row = t >> 1, half_ = t & 1;
    int l = l0 + row;
    int colbase = 4160 + half_ * 32;
#pragma unroll
    for (int j0 = 0; j0 < 32; j0 += 4) {
      float cv[4];
      conv4b(zx, cw, cb, l, colbase + j0, cv);
      int colc = half_ * 32 + j0;
      int quad = colc >> 3;
      int addr = row * 64 + ((quad ^ (row & 7)) << 3) + (colc & 7);
      *(ushort4*)&CS[addr] = make_ushort4(f2h(cv[0]), f2h(cv[1]), f2h(cv[2]), f2h(cv[3]));
    }
    __syncthreads();
#pragma unroll
    for (int ks = 0; ks < 2; ++ks)
#pragma unroll
      for (int ti = 0; ti < 2; ++ti) {
        int rw = t0 + ti * 16 + ml;
        int ad = rw * 64 + (((ks * 4 + g4) ^ (rw & 7)) << 3);
        cf[ks][ti] = *(const half8*)&CS[ad];
      }
  }

  f32x4 accY[2][4];
#pragma unroll
  for (int i = 0; i < 2; ++i)
#pragma unroll
    for (int j = 0; j < 4; ++j) accY[i][j] = (f32x4){0.f, 0.f, 0.f, 0.f};

  const float* xcv = ybuf;   // materialized conv'd X (in-place region)

  // ---- intra-chunk: 4 s-slabs ----
  for (int slab = 0; slab < 4; ++slab) {
    __syncthreads();   // staging overwrite vs previous phase reads / C-scratch
#pragma unroll
    for (int i = 0; i < 2; ++i) {
      int q = t + i * 256;
      int s = q >> 4, n4 = (q & 15) * 4;
      int l = l0 + slab * 32 + s;
      float4 v = *(const float4*)(bconv + (size_t)l * D_STATE + n4);
      ushort* B = (n4 < 32) ? Bsl0 : Bsl1;
      int jj = n4 & 31;
      *(ushort4*)&B[s * 40 + jj] = make_ushort4(f2h(v.x), f2h(v.y), f2h(v.z), f2h(v.w));
    }
    // stage X p-half (64 p x 32 s): s-contiguous ushort4 writes
#pragma unroll
    for (int i = 0; i < 2; ++i) {
      int q = t + i * 256;
      int p = q & 63, sg = q >> 6;
      ushort hh[4];
#pragma unroll
      for (int j = 0; j < 4; ++j) {
        int l = l0 + slab * 32 + sg * 4 + j;
        hh[j] = f2h(xcv[(size_t)l * D_INNER + h * HEADDIM + pbase + p]);
      }
      *(ushort4*)&Xt[p * 40 + sg * 4] = make_ushort4(hh[0], hh[1], hh[2], hh[3]);
    }
    __syncthreads();

    if (wave >= slab) {        // slabs > wave are exactly zero after the mask
      f32x4 g[2][2];
#pragma unroll
      for (int i = 0; i < 2; ++i)
#pragma unroll
        for (int j = 0; j < 2; ++j) g[i][j] = (f32x4){0.f, 0.f, 0.f, 0.f};
#pragma unroll
      for (int ks = 0; ks < 2; ++ks) {
        const ushort* B = ks ? Bsl1 : Bsl0;
#pragma unroll
        for (int si = 0; si < 2; ++si) {
          half8 bh = *(const half8*)&B[(si * 16 + ml) * 40 + g4 * 8];
#pragma unroll
          for (int ti = 0; ti < 2; ++ti)
            g[ti][si] = __builtin_amdgcn_mfma_f32_16x16x32_f16(cf[ks][ti], bh, g[ti][si], 0, 0, 0);
        }
      }
#pragma unroll
      for (int ti = 0; ti < 2; ++ti)
#pragma unroll
        for (int si = 0; si < 2; ++si) {
          int sl = si * 16 + ml;
          int sg = slab * 32 + sl;
#pragma unroll
          for (int r = 0; r < 4; ++r) {
            int tg = t0 + ti * 16 + g4 * 4 + r;
            float coeff = (sg <= tg) ? __expf(cum[tg] - cum[sg]) : 0.f;
            float val = g[ti][si][r] * coeff + ((sg == tg) ? Dh : 0.f);
            Msl[tg * 40 + sl] = f2h(val);
          }
        }
      asm volatile("s_waitcnt lgkmcnt(0)" ::: "memory");
      half8 ma[2];
#pragma unroll
      for (int ti = 0; ti < 2; ++ti)
        ma[ti] = *(const half8*)&Msl[(t0 + ti * 16 + ml) * 40 + g4 * 8];
#pragma unroll
      for (int pi = 0; pi < 4; ++pi) {
        half8 xh = *(const half8*)&Xt[(pi * 16 + ml) * 40 + g4 * 8];
#pragma unroll
        for (int ti = 0; ti < 2; ++ti)
          accY[ti][pi] = __builtin_amdgcn_mfma_f32_16x16x32_f16(ma[ti], xh, accY[ti][pi], 0, 0, 0);
      }
    }
  }

  // ---- inter-chunk: Y += diag(exp(cum)) C . S_init (p-half) ----
  const float* S = Sc + (size_t)blk * (HEADDIM * D_STATE);
#pragma unroll
  for (int ns = 0; ns < 2; ++ns) {
    __syncthreads();
#pragma unroll
    for (int i = 0; i < 2; ++i) {
      int q = t + i * 256;
      int p = q >> 3, j4 = (q & 7) * 4;
      float4 v = *(const float4*)(S + (size_t)(pbase + p) * D_STATE + ns * 32 + j4);
      *(ushort4*)&Xt[p * 40 + j4] = make_ushort4(f2h(v.x), f2h(v.y), f2h(v.z), f2h(v.w));
    }
    __syncthreads();
    half8 ma[2];
#pragma unroll
    for (int ti = 0; ti < 2; ++ti) {
      float e = __expf(cum[t0 + ti * 16 + ml]);
#pragma unroll
      for (int j = 0; j < 8; ++j)
        ma[ti][j] = (_Float16)((float)cf[ns][ti][j] * e);
    }
#pragma unroll
    for (int pi = 0; pi < 4; ++pi) {
      half8 xh = *(const half8*)&Xt[(pi * 16 + ml) * 40 + g4 * 8];
#pragma unroll
      for (int ti = 0; ti < 2; ++ti)
        accY[ti][pi] = __builtin_amdgcn_mfma_f32_16x16x32_f16(ma[ti], xh, accY[ti][pi], 0, 0, 0);
    }
  }

  // ---- epilogue: y = accY (overwrites this block's xconv p-half) ----
#pragma unroll
  for (int ti = 0; ti < 2; ++ti)
#pragma unroll
    for (int pi = 0; pi < 4; ++pi) {
      int p = pbase + pi * 16 + ml;
#pragma unroll
      for (int r = 0; r < 4; ++r) {
        int l = l0 + t0 + ti * 16 + g4 * 4 + r;
        ybuf[(size_t)l * D_INNER + h * HEADDIM + p] = accY[ti][pi][r];
      }
    }
}

// ------- RMSNorm + sigmoid(z) gate, emits gated y as FP16 (feeds f16 GEMM) ---
__launch_bounds__(256)
__global__ void rmsnorm_gate_split(const float* __restrict__ ybuf,
                                   const ushort* __restrict__ zx,
                                   const float* __restrict__ rms_w,
                                   ushort* __restrict__ yh) {
  const int row = blockIdx.x;
  const int t   = threadIdx.x;
  const float* y  = ybuf + (size_t)row * D_INNER;
  const ushort* z = zx   + (size_t)row * ZX_LD;      // z cols [0,2048)

  float4 a  = *(const float4*)(y + t * 8);
  float4 bq = *(const float4*)(y + t * 8 + 4);
  float ss = a.x * a.x + a.y * a.y + a.z * a.z + a.w * a.w +
             bq.x * bq.x + bq.y * bq.y + bq.z * bq.z + bq.w * bq.w;
#pragma unroll
  for (int off = 32; off > 0; off >>= 1) ss += __shfl_down(ss, off);
  __shared__ float red[4];
  if ((t & 63) == 0) red[t >> 6] = ss;
  __syncthreads();
  float tot = red[0] + red[1] + red[2] + red[3];
  float scale = rsqrtf(tot * (1.f / (float)D_INNER) + RMS_EPS);

  float vy[8] = {a.x, a.y, a.z, a.w, bq.x, bq.y, bq.z, bq.w};
  ushort4 zv0 = *(const ushort4*)(z + t * 8);
  ushort4 zv1 = *(const ushort4*)(z + t * 8 + 4);
  ushort zz[8] = {zv0.x, zv0.y, zv0.z, zv0.w, zv1.x, zv1.y, zv1.z, zv1.w};
  ushort hh[8];
#pragma unroll
  for (int jj = 0; jj < 8; ++jj) {
    int col = t * 8 + jj;
    float g = 1.f / (1.f + __expf(-bf2f(zz[jj])));
    float v = vy[jj] * scale * rms_w[col] * g;
    hh[jj] = f2h(v);
  }
  size_t o = (size_t)row * D_INNER + t * 8;
  *(ushort4*)(yh + o)     = make_ushort4(hh[0], hh[1], hh[2], hh[3]);
  *(ushort4*)(yh + o + 4) = make_ushort4(hh[4], hh[5], hh[6], hh[7]);
}

// ---------------- launch ----------------
// ws layout identical (129.8 MB). f16 planes overwrite unused bf16 regions:
// w1f16 = w1h rows [0,4224) (dt rows preserved), w2f16 = w2h, uf16 = ybuf
// overlay (dead until passA).
extern "C" void kernel_launch(void* const* d_in, const int* in_sizes, int n_in,
                              void* d_out, int out_size, void* d_ws, size_t ws_size,
                              hipStream_t stream) {
  const float* u         = (const float*)d_in[0];
  const float* in_proj_w = (const float*)d_in[1];
  const float* conv_w    = (const float*)d_in[2];
  const float* conv_b    = (const float*)d_in[3];
  const float* dt_bias   = (const float*)d_in[4];
  const float* A_log     = (const float*)d_in[5];
  const float* Dp        = (const float*)d_in[6];
  const float* rms_w     = (const float*)d_in[7];
  const float* out_w     = (const float*)d_in[8];
  float* out = (float*)d_out;

  float* ws    = (float*)d_ws;
  ushort* zxbc = (ushort*)ws;                                  // [4096, 4224] bf16
  float* dtb   = ws   + (size_t)SEQLEN * ZX_LD / 2;            // [4096, 16]
  float* dtp   = dtb  + (size_t)SEQLEN * NHEADS;               // [8, 4096, 16]
  float* ybuf  = dtp  + (size_t)8 * SEQLEN * NHEADS;           // [4096, 2048]
  float* Pc    = ybuf + (size_t)SEQLEN * D_INNER;              // [512]
  float* Sc    = Pc   + 512;                                   // [512, 8192]
  ushort* uh   = (ushort*)(Sc + (size_t)NHEADS * NCHUNK * HEADDIM * D_STATE);
  ushort* ul   = uh  + (size_t)SEQLEN * D_MODEL;
  ushort* w1h  = ul  + (size_t)SEQLEN * D_MODEL;
  ushort* w1l  = w1h + (size_t)D_IN_PROJ * D_MODEL;
  ushort* w2h  = w1l + (size_t)D_IN_PROJ * D_MODEL;
  ushort* w2l  = w2h + (size_t)D_MODEL * D_INNER;
  ushort* yh   = (ushort*)Sc;                                  // overlay Sc (dead)
  float* Opart = ybuf;                                         // overlay ybuf (dead)
  float* bconv = dtp;                                          // overlay dtp (dead)
  ushort* uf16 = (ushort*)ybuf;                                // overlay ybuf (pre-passA)

  // weight conversions (once per call): bf16 hi/lo for dt rows, f16 elsewhere
  {
    int n4 = D_IN_PROJ * D_MODEL / 4;
    cvt_split<<<(n4 + 255) / 256, 256, 0, stream>>>(in_proj_w, w1h, w1l, n4);
    int z4 = ZX_LD * D_MODEL / 4;     // overwrite rows [0,4224) of w1h with f16
    cvt_f16<<<(z4 + 255) / 256, 256, 0, stream>>>(in_proj_w, w1h, z4);
    int m4 = D_MODEL * D_INNER / 4;
    cvt_f16<<<(m4 + 255) / 256, 256, 0, stream>>>(out_w, w2h, m4);
  }

  for (int b = 0; b < BATCH; ++b) {
    const float* u_b  = u   + (size_t)b * SEQLEN * D_MODEL;
    float*      out_b = out + (size_t)b * SEQLEN * D_MODEL;

    // 0) u_b -> bf16 hi/lo + f16 plane in ONE pass (u read once)
    {
      int n4 = SEQLEN * D_MODEL / 4;
      cvt_u3<<<(n4 + 255) / 256, 256, 0, stream>>>(u_b, uh, ul, uf16, n4);
    }

    // 1) merged z|x|B|C GEMM — f16, single-buffered 128^2 @ 4 blocks/CU
    {
      dim3 g(40, SEQLEN / 128, 1);
      gemm_f16<128, 64, true, false><<<g, 256, 0, stream>>>(uf16, w1h, (float*)zxbc,
                                                            ZX_LD, SEQLEN, ZX_LD,
                                                            D_MODEL, D_MODEL);
    }
    // 1b) dt GEMM (3-term bf16, split-K=8): N=16, near-fp32 (feeds exponentials)
    {
      const ushort* bh = w1h + (size_t)ZX_LD * D_MODEL;
      const ushort* bl = w1l + (size_t)ZX_LD * D_MODEL;
      dim3 g(1, SEQLEN / 128, 8);
      gemm_bf16p<128, 32, true, false><<<g, 256, 0, stream>>>(uh, ul, bh, bl,
                                                          dtp, NHEADS, SEQLEN, NHEADS,
                                                          D_MODEL, D_MODEL / 8, 0);
      add_dt<<<(SEQLEN * NHEADS / 4 + 255) / 256, 256, 0, stream>>>(dtp, dtb);
    }

    // 2-4) SSD chunked scan on MFMA (f16 operands, p-split grids: 4 blocks/CU)
    passA_ssd<<<dim3(NHEADS * NCHUNK, 2), 256, 0, stream>>>(zxbc, dtb, conv_w, conv_b,
                                                            dt_bias, A_log, Sc, Pc,
                                                            ybuf, bconv);
    scan_passB<<<dim3(NHEADS, (HEADDIM * D_STATE) / 512), 512, 0, stream>>>(Sc, Pc);
    passC_ssd<<<dim3(NHEADS * NCHUNK, 2), 256, 0, stream>>>(zxbc, dtb, conv_w, conv_b,
                                                            dt_bias, A_log, Dp, Sc,
                                                            bconv, ybuf);

    // 5) RMSNorm + gate -> y f16 (overlays Sc, dead now)
    rmsnorm_gate_split<<<SEQLEN, 256, 0, stream>>>(ybuf, zxbc, rms_w, yh);

    // 6) out GEMM, split-K=2 (512 blocks = 2/CU): depth-2 pipelined
    {
      dim3 g(D_MODEL / 128, SEQLEN / 128, 2);
      gemm_f16<128, 64, false, true><<<g, 256, 0, stream>>>(yh, w2h, Opart, D_MODEL,
                                                            SEQLEN, D_MODEL,
                                                            D_INNER, D_INNER / 2);
    }
    // 7) combine partials -> out_b
    add_out<<<(SEQLEN * D_MODEL / 4 + 255) / 256, 256, 0, stream>>>(Opart, out_b,
                                                                    SEQLEN * D_MODEL / 4);
  }
}

// Round 13
// 455.064 us; speedup vs baseline: 1.1919x; 1.0155x over previous
//
#include <hip/hip_runtime.h>
#include <math.h>

// ---------------- problem constants ----------------
#define D_MODEL   1024
#define D_INNER   2048
#define D_STATE   64
#define HEADDIM   128
#define NHEADS    16
#define D_CONV    4
#define BATCH     2
#define SEQLEN    4096
#define RMS_EPS   1e-5f
#define D_IN_PROJ 4240

// zxbc buffer (bf16): cols [0,2048)=z, [2048,4096)=x, [4096,4160)=B, [4160,4224)=C
#define ZX_LD     4224

#define LCHUNK    128
#define NCHUNK    (SEQLEN / LCHUNK)   // 32

typedef __attribute__((ext_vector_type(8))) short short8;
typedef __attribute__((ext_vector_type(4))) float f32x4;
typedef _Float16 half8 __attribute__((ext_vector_type(8)));

__device__ __forceinline__ ushort f2bf(float f) {
  unsigned u = __float_as_uint(f);
  u += 0x7fff + ((u >> 16) & 1);          // RNE
  return (ushort)(u >> 16);
}
__device__ __forceinline__ float bf2f(ushort h) {
  return __uint_as_float(((unsigned)h) << 16);
}
__device__ __forceinline__ ushort f2h(float f) {
  _Float16 h = (_Float16)f;               // RNE
  ushort u; __builtin_memcpy(&u, &h, 2); return u;
}
__device__ __forceinline__ void ld4(const float* p, float* d) {
  float4 v = *(const float4*)p; d[0] = v.x; d[1] = v.y; d[2] = v.z; d[3] = v.w;
}
__device__ __forceinline__ void ld4b(const ushort* p, float* d) {
  ushort4 v = *(const ushort4*)p;
  d[0] = bf2f(v.x); d[1] = bf2f(v.y); d[2] = bf2f(v.z); d[3] = bf2f(v.w);
}

// async global->LDS, 16B per lane (global_load_lds_dwordx4)
__device__ __forceinline__ void gl_lds16(const ushort* g, ushort* l) {
  __builtin_amdgcn_global_load_lds(
      (const __attribute__((address_space(1))) unsigned int*)g,
      (__attribute__((address_space(3))) unsigned int*)l, 16, 0, 0);
}

// ---------------- split fp32 -> bf16 hi/lo planes (weights) ----------------
__global__ void cvt_split(const float* __restrict__ w,
                          ushort* __restrict__ hi, ushort* __restrict__ lo, int n4) {
  int i = blockIdx.x * 256 + threadIdx.x;
  if (i >= n4) return;
  float4 v = ((const float4*)w)[i];
  ushort h0 = f2bf(v.x), h1 = f2bf(v.y), h2 = f2bf(v.z), h3 = f2bf(v.w);
  ushort l0 = f2bf(v.x - bf2f(h0)), l1 = f2bf(v.y - bf2f(h1));
  ushort l2 = f2bf(v.z - bf2f(h2)), l3 = f2bf(v.w - bf2f(h3));
  ((ushort4*)hi)[i] = make_ushort4(h0, h1, h2, h3);
  ((ushort4*)lo)[i] = make_ushort4(l0, l1, l2, l3);
}

// ---------------- fp32 -> fp16 plane ----------------
__global__ void cvt_f16(const float* __restrict__ w, ushort* __restrict__ o, int n4) {
  int i = blockIdx.x * 256 + threadIdx.x;
  if (i >= n4) return;
  float4 v = ((const float4*)w)[i];
  ((ushort4*)o)[i] = make_ushort4(f2h(v.x), f2h(v.y), f2h(v.z), f2h(v.w));
}

// --------- u: one fp32 read -> bf16 hi/lo (dt GEMM) + f16 (in-proj) ---------
__global__ void cvt_u3(const float* __restrict__ w, ushort* __restrict__ hi,
                       ushort* __restrict__ lo, ushort* __restrict__ h16, int n4) {
  int i = blockIdx.x * 256 + threadIdx.x;
  if (i >= n4) return;
  float4 v = ((const float4*)w)[i];
  ushort h0 = f2bf(v.x), h1 = f2bf(v.y), h2 = f2bf(v.z), h3 = f2bf(v.w);
  ((ushort4*)hi)[i]  = make_ushort4(h0, h1, h2, h3);
  ((ushort4*)lo)[i]  = make_ushort4(f2bf(v.x - bf2f(h0)), f2bf(v.y - bf2f(h1)),
                                    f2bf(v.z - bf2f(h2)), f2bf(v.w - bf2f(h3)));
  ((ushort4*)h16)[i] = make_ushort4(f2h(v.x), f2h(v.y), f2h(v.z), f2h(v.w));
}

// ---------------- bf16-plane split NT GEMM (single-buffered; dt GEMM only) ---
template<int BM, int BK, bool ALO, bool OBF16>
__launch_bounds__(256, 3)
__global__ void gemm_bf16p(const ushort* __restrict__ Ah, const ushort* __restrict__ Al,
                           const ushort* __restrict__ Bh, const ushort* __restrict__ Bl,
                           float* __restrict__ C, int ldc,
                           int M, int N, int ldab, int Kslice, int n1term) {
  constexpr int BN = 128;
  constexpr int NQ = BK / 8;
  constexpr int RT = BM / 32;
  constexpr int CT = 4;
  constexpr int KS = BK / 32;

  __shared__ ushort As[ALO ? 2 : 1][BM * BK];
  __shared__ ushort Bs[2][BN * BK];

  const int bn   = blockIdx.x * BN;
  if (bn >= N) return;
  const bool two = (bn >= n1term);
  const int t    = threadIdx.x;
  const int bm   = blockIdx.y * BM;
  const int kz   = blockIdx.z;
  const int kb   = kz * Kslice;
  C += (size_t)kz * M * ldc;
  const int wave = t >> 6, lane = t & 63;
  const int ml   = lane & 15, g4 = lane >> 4;
  const int sw   = ml & (NQ - 1);
  const int wr   = wave & 1, wc = wave >> 1;
  const int r0   = wr * RT * 16, c0 = wc * CT * 16;

  f32x4 acc[RT][CT];
#pragma unroll
  for (int i = 0; i < RT; ++i)
#pragma unroll
    for (int j = 0; j < CT; ++j) acc[i][j] = (f32x4){0.f, 0.f, 0.f, 0.f};

  for (int k0 = kb; k0 < kb + Kslice; k0 += BK) {
    __syncthreads();
#pragma unroll
    for (int ii = 0; ii < BM * NQ / 256; ++ii) {
      int idx = t + ii * 256;
      int row = idx / NQ, qs = idx % NQ;
      int qg  = qs ^ (row & (NQ - 1));
      size_t go = (size_t)(bm + row) * ldab + k0 + qg * 8;
      gl_lds16(Ah + go, &As[0][idx * 8]);
      if (ALO) gl_lds16(Al + go, &As[ALO ? 1 : 0][idx * 8]);
    }
#pragma unroll
    for (int ii = 0; ii < BN * NQ / 256; ++ii) {
      int idx = t + ii * 256;
      int row = idx / NQ, qs = idx % NQ;
      int qg  = qs ^ (row & (NQ - 1));
      size_t go = (size_t)(bn + row) * ldab + k0 + qg * 8;
      gl_lds16(Bh + go, &Bs[0][idx * 8]);
      if (two) gl_lds16(Bl + go, &Bs[1][idx * 8]);
    }
    __syncthreads();

#pragma unroll
    for (int ks = 0; ks < KS; ++ks) {
      const int qA = ((ks * 4 + g4) ^ sw) * 8;
      short8 ah[RT], al[RT], bh[CT], bl[CT];
#pragma unroll
      for (int i = 0; i < RT; ++i) {
        int off = (r0 + i * 16 + ml) * BK + qA;
        ah[i] = *(const short8*)&As[0][off];
        if (ALO) al[i] = *(const short8*)&As[ALO ? 1 : 0][off];
      }
#pragma unroll
      for (int j = 0; j < CT; ++j) {
        int off = (c0 + j * 16 + ml) * BK + qA;
        bh[j] = *(const short8*)&Bs[0][off];
        if (two) bl[j] = *(const short8*)&Bs[1][off];
      }
#pragma unroll
      for (int i = 0; i < RT; ++i)
#pragma unroll
        for (int j = 0; j < CT; ++j) {
          acc[i][j] = __builtin_amdgcn_mfma_f32_16x16x32_bf16(ah[i], bh[j], acc[i][j], 0, 0, 0);
          if (two)
            acc[i][j] = __builtin_amdgcn_mfma_f32_16x16x32_bf16(ah[i], bl[j], acc[i][j], 0, 0, 0);
          if (ALO)
            acc[i][j] = __builtin_amdgcn_mfma_f32_16x16x32_bf16(al[i], bh[j], acc[i][j], 0, 0, 0);
        }
    }
  }

#pragma unroll
  for (int i = 0; i < RT; ++i)
#pragma unroll
    for (int j = 0; j < CT; ++j) {
      int col = bn + c0 + j * 16 + ml;
      if (col < N) {
        int rowb = bm + r0 + i * 16 + g4 * 4;
#pragma unroll
        for (int r = 0; r < 4; ++r) {
          if (OBF16) ((ushort*)C)[(size_t)(rowb + r) * ldc + col] = f2bf(acc[i][j][r]);
          else       C[(size_t)(rowb + r) * ldc + col] = acc[i][j][r];
        }
      }
    }
}

// ---------------- single-plane FP16 NT GEMM (BN=128-col tiles) ----------------
// PIPE=false: single-buffered, (256,4): 4 blocks/CU (R10: (256,5) spilled).
// PIPE=true: depth-2 counted-vmcnt pipeline for 2-block/CU grid-limited sites.
// vmcnt literal dispatched on loads-per-stage (BM=128 -> 8, BM=64 -> 6).
template<int BM, int BK, bool OBF16, bool PIPE>
__launch_bounds__(256, PIPE ? 2 : 4)
__global__ void gemm_f16(const ushort* __restrict__ Ah, const ushort* __restrict__ Bh,
                         float* __restrict__ C, int ldc,
                         int M, int N, int ldab, int Kslice) {
  constexpr int BN = 128;
  constexpr int NQ = BK / 8;
  constexpr int RT = BM / 32;
  constexpr int CT = 4;
  constexpr int KS = BK / 32;
  constexpr int NBUF = PIPE ? 2 : 1;
  constexpr int LPT = (BM + BN) * NQ / 256;   // loads/thread/stage

  __shared__ ushort As[NBUF][BM * BK];
  __shared__ ushort Bs[NBUF][BN * BK];

  const int bn   = blockIdx.x * BN;
  if (bn >= N) return;                     // padded grid.x tiles exit
  const int t    = threadIdx.x;
  const int bm   = blockIdx.y * BM;
  const int kz   = blockIdx.z;
  const int kb   = kz * Kslice;
  C += (size_t)kz * M * ldc;
  const int wave = t >> 6, lane = t & 63;
  const int ml   = lane & 15, g4 = lane >> 4;
  const int sw   = ml & (NQ - 1);
  const int wr   = wave & 1, wc = wave >> 1;
  const int r0   = wr * RT * 16, c0 = wc * CT * 16;

  f32x4 acc[RT][CT];
#pragma unroll
  for (int i = 0; i < RT; ++i)
#pragma unroll
    for (int j = 0; j < CT; ++j) acc[i][j] = (f32x4){0.f, 0.f, 0.f, 0.f};

  auto stage = [&](int k0, int buf) {
#pragma unroll
    for (int ii = 0; ii < BM * NQ / 256; ++ii) {
      int idx = t + ii * 256;
      int row = idx / NQ, qs = idx % NQ;
      int qg  = qs ^ (row & (NQ - 1));
      size_t go = (size_t)(bm + row) * ldab + k0 + qg * 8;
      gl_lds16(Ah + go, &As[buf][idx * 8]);
    }
#pragma unroll
    for (int ii = 0; ii < BN * NQ / 256; ++ii) {
      int idx = t + ii * 256;
      int row = idx / NQ, qs = idx % NQ;
      int qg  = qs ^ (row & (NQ - 1));
      size_t go = (size_t)(bn + row) * ldab + k0 + qg * 8;   // rows past N read
      gl_lds16(Bh + go, &Bs[buf][idx * 8]);                  // adjacent valid memory
    }
  };

  auto compute = [&](int buf) {
#pragma unroll
    for (int ks = 0; ks < KS; ++ks) {
      const int qA = ((ks * 4 + g4) ^ sw) * 8;
      half8 ah[RT], bh[CT];
#pragma unroll
      for (int i = 0; i < RT; ++i)
        ah[i] = *(const half8*)&As[buf][(r0 + i * 16 + ml) * BK + qA];
#pragma unroll
      for (int j = 0; j < CT; ++j)
        bh[j] = *(const half8*)&Bs[buf][(c0 + j * 16 + ml) * BK + qA];
#pragma unroll
      for (int i = 0; i < RT; ++i)
#pragma unroll
        for (int j = 0; j < CT; ++j)
          acc[i][j] = __builtin_amdgcn_mfma_f32_16x16x32_f16(ah[i], bh[j], acc[i][j], 0, 0, 0);
    }
  };

  if (PIPE) {
    const int NIT = Kslice / BK;
    stage(kb, 0);
    if (NIT > 1) stage(kb + BK, 1);
    for (int it = 0; it < NIT; ++it) {
      const int buf = it & 1;
      if (it + 1 < NIT) {
        if constexpr (LPT == 8)      asm volatile("s_waitcnt vmcnt(8)" ::: "memory");
        else if constexpr (LPT == 6) asm volatile("s_waitcnt vmcnt(6)" ::: "memory");
        else                         asm volatile("s_waitcnt vmcnt(0)" ::: "memory");
      } else {
        asm volatile("s_waitcnt vmcnt(0)" ::: "memory");
      }
      __builtin_amdgcn_s_barrier();        // all waves' stage(it) landed
      __builtin_amdgcn_sched_barrier(0);
      compute(buf);
      __builtin_amdgcn_sched_barrier(0);
      __builtin_amdgcn_s_barrier();        // all waves done reading buf
      __builtin_amdgcn_sched_barrier(0);
      if (it + 2 < NIT) stage(kb + (it + 2) * BK, buf);
    }
  } else {
    for (int k0 = kb; k0 < kb + Kslice; k0 += BK) {
      __syncthreads();
      stage(k0, 0);
      __syncthreads();
      compute(0);
    }
  }

#pragma unroll
  for (int i = 0; i < RT; ++i)
#pragma unroll
    for (int j = 0; j < CT; ++j) {
      int col = bn + c0 + j * 16 + ml;
      if (col < N) {
        int rowb = bm + r0 + i * 16 + g4 * 4;
#pragma unroll
        for (int r = 0; r < 4; ++r) {
          if (OBF16) ((ushort*)C)[(size_t)(rowb + r) * ldc + col] = f2bf(acc[i][j][r]);
          else       C[(size_t)(rowb + r) * ldc + col] = acc[i][j][r];
        }
      }
    }
}

// ---------------- combine dt split-K=8 partials ----------------
__global__ void add_dt(const float* __restrict__ P, float* __restrict__ dtb) {
  int i = blockIdx.x * 256 + threadIdx.x;
  if (i >= SEQLEN * NHEADS / 4) return;
  float4 s = ((const float4*)P)[i];
#pragma unroll
  for (int k = 1; k < 8; ++k) {
    float4 v = ((const float4*)(P + (size_t)k * SEQLEN * NHEADS))[i];
    s.x += v.x; s.y += v.y; s.z += v.z; s.w += v.w;
  }
  ((float4*)dtb)[i] = s;
}

// =================== SSD chunked scan on MFMA ===================
// f16 scan operands (R8-verified); p-split x2 grids for TLP (R12).

__device__ __forceinline__ void cum_scan(float* cum, float v, int t, float* carry) {
  int lane = t & 63;
#pragma unroll
  for (int off = 1; off < 64; off <<= 1) {
    float o = __shfl_up(v, off);
    if (lane >= off) v += o;
  }
  if (t == 63) *carry = v;
  __syncthreads();
  if (t >= 64 && t < LCHUNK) v += *carry;
  if (t < LCHUNK) cum[t] = v;
  __syncthreads();
}

// conv+silu at (l, zxbc-col): channel = col - 2048; taps read bf16 rows above.
__device__ __forceinline__ void conv4b(const ushort* __restrict__ zx,
                                       const float* __restrict__ cw,
                                       const float* __restrict__ cb,
                                       int l, int col0, float* outv) {
  const ushort* bp = zx + (size_t)l * ZX_LD + col0;
  float r3[4], r2[4], r1[4], r0[4], bb[4];
  ld4b(bp, r3);
  if (l >= 1) ld4b(bp - ZX_LD, r2);     else { r2[0]=r2[1]=r2[2]=r2[3]=0.f; }
  if (l >= 2) ld4b(bp - 2 * ZX_LD, r1); else { r1[0]=r1[1]=r1[2]=r1[3]=0.f; }
  if (l >= 3) ld4b(bp - 3 * ZX_LD, r0); else { r0[0]=r0[1]=r0[2]=r0[3]=0.f; }
  const int ch = col0 - 2048;
  ld4(cb + ch, bb);
#pragma unroll
  for (int j = 0; j < 4; ++j) {
    float w4[4]; ld4(cw + (ch + j) * 4, w4);
    float a = bb[j];
    a = fmaf(w4[0], r0[j], a);
    a = fmaf(w4[1], r1[j], a);
    a = fmaf(w4[2], r2[j], a);
    a = fmaf(w4[3], r3[j], a);
    outv[j] = a / (1.f + __expf(-a));
  }
}

// ---------------- pass A: per-chunk local state (f16, p-split x2) ------------
__launch_bounds__(256, 4)
__global__ void passA_ssd(const ushort* __restrict__ zx,
                          const float* __restrict__ dtb,
                          const float* __restrict__ cw, const float* __restrict__ cb,
                          const float* __restrict__ dt_bias,
                          const float* __restrict__ A_log,
                          float* __restrict__ Sc, float* __restrict__ Pc,
                          float* __restrict__ xconv, float* __restrict__ bconv) {
  const int blk = blockIdx.x;
  const int c   = blk & (NCHUNK - 1);
  const int h   = blk >> 5;
  const int ph  = blockIdx.y;           // p-half: p in [ph*64, ph*64+64)
  const int pbase = ph * 64;
  const int l0  = c * LCHUNK;
  const int t   = threadIdx.x;
  const int wave = t >> 6, lane = t & 63;
  const int ml = lane & 15, g4 = lane >> 4;
  const float Ah = -expf(A_log[h]);

  __shared__ float cum[LCHUNK];
  __shared__ float carry;
  __shared__ ushort Xt[64 * 40];
  __shared__ ushort Bt[D_STATE * 40];

  {
    float v = 0.f;
    if (t < LCHUNK) {
      float xv = dtb[(size_t)(l0 + t) * NHEADS + h] + dt_bias[h];
      float sp = (xv > 20.f) ? xv : log1pf(expf(xv));
      v = sp * Ah;
    }
    cum_scan(cum, v, t, &carry);
  }
  const float cend = cum[LCHUNK - 1];

  f32x4 acc[4];
#pragma unroll
  for (int j = 0; j < 4; ++j) acc[j] = (f32x4){0.f, 0.f, 0.f, 0.f};
  const int p0 = wave * 16;             // 4 waves x 16 = 64 local p rows

  for (int slab = 0; slab < 4; ++slab) {
    __syncthreads();
    // X conv for this p-half: 64 p x 32 s
    for (int i = 0; i < 2; ++i) {
      int q = t + i * 256;
      int s = q >> 4, p4 = (q & 15) * 4;
      int l = l0 + slab * 32 + s;
      float xv[4];
      conv4b(zx, cw, cb, l, 2048 + h * HEADDIM + pbase + p4, xv);
      *(float4*)(xconv + (size_t)l * D_INNER + h * HEADDIM + pbase + p4) =
          make_float4(xv[0], xv[1], xv[2], xv[3]);
#pragma unroll
      for (int j = 0; j < 4; ++j) Xt[(p4 + j) * 40 + s] = f2h(xv[j]);
    }
    // B conv (duplicated per half; bconv single-writer)
    for (int i = 0; i < 2; ++i) {
      int q = t + i * 256;
      int s = q >> 4, n4 = (q & 15) * 4;
      int l = l0 + slab * 32 + s;
      float wd = __expf(cend - cum[slab * 32 + s]);
      float bv[4];
      conv4b(zx, cw, cb, l, 4096 + n4, bv);
      if (h == 0 && ph == 0)
        *(float4*)(bconv + (size_t)l * D_STATE + n4) =
            make_float4(bv[0], bv[1], bv[2], bv[3]);
#pragma unroll
      for (int j = 0; j < 4; ++j) Bt[(n4 + j) * 40 + s] = f2h(bv[j] * wd);
    }
    __syncthreads();

    half8 xa = *(const half8*)&Xt[(p0 + ml) * 40 + g4 * 8];
#pragma unroll
    for (int ni = 0; ni < 4; ++ni) {
      half8 bh = *(const half8*)&Bt[(ni * 16 + ml) * 40 + g4 * 8];
      acc[ni] = __builtin_amdgcn_mfma_f32_16x16x32_f16(xa, bh, acc[ni], 0, 0, 0);
    }
  }

  float* S = Sc + (size_t)blk * (HEADDIM * D_STATE);
#pragma unroll
  for (int ni = 0; ni < 4; ++ni) {
    int n = ni * 16 + ml;
#pragma unroll
    for (int r = 0; r < 4; ++r) {
      int p = pbase + p0 + g4 * 4 + r;
      S[(size_t)p * D_STATE + n] = acc[ni][r];
    }
  }
  if (t == 0 && ph == 0) Pc[blk] = __expf(cend);
}

// ---------------- pass B: exclusive prefix over chunks ----------------
__global__ void scan_passB(float* __restrict__ Sc, const float* __restrict__ Pc) {
  const int h = blockIdx.x;
  const int e = blockIdx.y * 512 + threadIdx.x;
  const size_t hb = (size_t)h * NCHUNK;
  float st = 0.f;
  for (int c = 0; c < NCHUNK; ++c) {
    size_t idx = (hb + c) * (HEADDIM * D_STATE) + e;
    float P = Pc[hb + c];
    float v = Sc[idx];
    Sc[idx] = st;
    st = fmaf(P, st, v);
  }
}

// ---------------- pass C: intra-chunk attention (f16, p-split x2) ------------
// LDS carve (10240 ushorts = 20.5KB):
//   [0,1280) Bsl0  [1280,2560) Bsl1  [2560,7680) Msl(128x40)  [7680,10240) Xt(64x40)
__launch_bounds__(256, 4)
__global__ void passC_ssd(const ushort* __restrict__ zx,
                          const float* __restrict__ dtb,
                          const float* __restrict__ cw, const float* __restrict__ cb,
                          const float* __restrict__ dt_bias,
                          const float* __restrict__ A_log,
                          const float* __restrict__ Dp,
                          const float* __restrict__ Sc,
                          const float* __restrict__ bconv,
                          float* __restrict__ ybuf) {
  const int blk = blockIdx.x;
  const int c   = blk & (NCHUNK - 1);
  const int h   = blk >> 5;
  const int ph  = blockIdx.y;           // p-half
  const int pbase = ph * 64;
  const int l0  = c * LCHUNK;
  const int t   = threadIdx.x;
  const int wave = t >> 6, lane = t & 63;
  const int ml = lane & 15, g4 = lane >> 4;
  const int t0 = wave * 32;
  const float Ah = -expf(A_log[h]);
  const float Dh = Dp[h];

  __shared__ float cum[LCHUNK];
  __shared__ float carry;
  __shared__ ushort ldsb[10240];
  ushort* Bsl0 = ldsb;
  ushort* Bsl1 = ldsb + 1280;
  ushort* Msl  = ldsb + 2560;
  ushort* Xt   = ldsb + 7680;

  {
    float v = 0.f;
    if (t < LCHUNK) {
      float xv = dtb[(size_t)(l0 + t) * NHEADS + h] + dt_bias[h];
      float sp = (xv > 20.f) ? xv : log1pf(expf(xv));
      v = sp * Ah;
    }
    cum_scan(cum, v, t, &carry);
  }

  // ---- C conv -> swizzled scratch (ldsb[0,8192)), then f16 register frags --
  half8 cf[2][2];
  {
    ushort* CS = ldsb;
    int row = t >> 1, half_ = t & 1;
    int l = l0 + row;
    int colbase = 4160 + half_ * 32;
#pragma unroll
    for (int j0 = 0; j0 < 32; j0 += 4) {
      float cv[4];
      conv4b(zx, cw, cb, l, colbase + j0, cv);
      int colc = half_ * 32 + j0;
      int quad = colc >> 3;
      int addr = row * 64 + ((quad ^ (row & 7)) << 3) + (colc & 7);
      *(ushort4*)&CS[addr] = make_ushort4(f2h(cv[0]), f2h(cv[1]), f2h(cv[2]), f2h(cv[3]));
    }
    __syncthreads();
#pragma unroll
    for (int ks = 0; ks < 2; ++ks)
#pragma unroll
      for (int ti = 0; ti < 2; ++ti) {
        int rw = t0 + ti * 16 + ml;
        int ad = rw * 64 + (((ks * 4 + g4) ^ (rw & 7)) << 3);
        cf[ks][ti] = *(const half8*)&CS[ad];
      }
  }

  f32x4 accY[2][4];
#pragma unroll
  for (int i = 0; i < 2; ++i)
#pragma unroll
    for (int j = 0; j < 4; ++j) accY[i][j] = (f32x4){0.f, 0.f, 0.f, 0.f};

  const float* xcv = ybuf;   // materialized conv'd X (in-place region)

  // ---- intra-chunk: 4 s-slabs ----
  for (int slab = 0; slab < 4; ++slab) {
    __syncthreads();   // staging overwrite vs previous phase reads / C-scratch
#pragma unroll
    for (int i = 0; i < 2; ++i) {
      int q = t + i * 256;
      int s = q >> 4, n4 = (q & 15) * 4;
      int l = l0 + slab * 32 + s;
      float4 v = *(const float4*)(bconv + (size_t)l * D_STATE + n4);
      ushort* B = (n4 < 32) ? Bsl0 : Bsl1;
      int jj = n4 & 31;
      *(ushort4*)&B[s * 40 + jj] = make_ushort4(f2h(v.x), f2h(v.y), f2h(v.z), f2h(v.w));
    }
    // stage X p-half (64 p x 32 s): s-contiguous ushort4 writes
#pragma unroll
    for (int i = 0; i < 2; ++i) {
      int q = t + i * 256;
      int p = q & 63, sg = q >> 6;
      ushort hh[4];
#pragma unroll
      for (int j = 0; j < 4; ++j) {
        int l = l0 + slab * 32 + sg * 4 + j;
        hh[j] = f2h(xcv[(size_t)l * D_INNER + h * HEADDIM + pbase + p]);
      }
      *(ushort4*)&Xt[p * 40 + sg * 4] = make_ushort4(hh[0], hh[1], hh[2], hh[3]);
    }
    __syncthreads();

    if (wave >= slab) {        // slabs > wave are exactly zero after the mask
      f32x4 g[2][2];
#pragma unroll
      for (int i = 0; i < 2; ++i)
#pragma unroll
        for (int j = 0; j < 2; ++j) g[i][j] = (f32x4){0.f, 0.f, 0.f, 0.f};
#pragma unroll
      for (int ks = 0; ks < 2; ++ks) {
        const ushort* B = ks ? Bsl1 : Bsl0;
#pragma unroll
        for (int si = 0; si < 2; ++si) {
          half8 bh = *(const half8*)&B[(si * 16 + ml) * 40 + g4 * 8];
#pragma unroll
          for (int ti = 0; ti < 2; ++ti)
            g[ti][si] = __builtin_amdgcn_mfma_f32_16x16x32_f16(cf[ks][ti], bh, g[ti][si], 0, 0, 0);
        }
      }
#pragma unroll
      for (int ti = 0; ti < 2; ++ti)
#pragma unroll
        for (int si = 0; si < 2; ++si) {
          int sl = si * 16 + ml;
          int sg = slab * 32 + sl;
#pragma unroll
          for (int r = 0; r < 4; ++r) {
            int tg = t0 + ti * 16 + g4 * 4 + r;
            float coeff = (sg <= tg) ? __expf(cum[tg] - cum[sg]) : 0.f;
            float val = g[ti][si][r] * coeff + ((sg == tg) ? Dh : 0.f);
            Msl[tg * 40 + sl] = f2h(val);
          }
        }
      asm volatile("s_waitcnt lgkmcnt(0)" ::: "memory");
      half8 ma[2];
#pragma unroll
      for (int ti = 0; ti < 2; ++ti)
        ma[ti] = *(const half8*)&Msl[(t0 + ti * 16 + ml) * 40 + g4 * 8];
#pragma unroll
      for (int pi = 0; pi < 4; ++pi) {
        half8 xh = *(const half8*)&Xt[(pi * 16 + ml) * 40 + g4 * 8];
#pragma unroll
        for (int ti = 0; ti < 2; ++ti)
          accY[ti][pi] = __builtin_amdgcn_mfma_f32_16x16x32_f16(ma[ti], xh, accY[ti][pi], 0, 0, 0);
      }
    }
  }

  // ---- inter-chunk: Y += diag(exp(cum)) C . S_init (p-half) ----
  const float* S = Sc + (size_t)blk * (HEADDIM * D_STATE);
#pragma unroll
  for (int ns = 0; ns < 2; ++ns) {
    __syncthreads();
#pragma unroll
    for (int i = 0; i < 2; ++i) {
      int q = t + i * 256;
      int p = q >> 3, j4 = (q & 7) * 4;
      float4 v = *(const float4*)(S + (size_t)(pbase + p) * D_STATE + ns * 32 + j4);
      *(ushort4*)&Xt[p * 40 + j4] = make_ushort4(f2h(v.x), f2h(v.y), f2h(v.z), f2h(v.w));
    }
    __syncthreads();
    half8 ma[2];
#pragma unroll
    for (int ti = 0; ti < 2; ++ti) {
      float e = __expf(cum[t0 + ti * 16 + ml]);
#pragma unroll
      for (int j = 0; j < 8; ++j)
        ma[ti][j] = (_Float16)((float)cf[ns][ti][j] * e);
    }
#pragma unroll
    for (int pi = 0; pi < 4; ++pi) {
      half8 xh = *(const half8*)&Xt[(pi * 16 + ml) * 40 + g4 * 8];
#pragma unroll
      for (int ti = 0; ti < 2; ++ti)
        accY[ti][pi] = __builtin_amdgcn_mfma_f32_16x16x32_f16(ma[ti], xh, accY[ti][pi], 0, 0, 0);
    }
  }

  // ---- epilogue: y = accY (overwrites this block's xconv p-half) ----
#pragma unroll
  for (int ti = 0; ti < 2; ++ti)
#pragma unroll
    for (int pi = 0; pi < 4; ++pi) {
      int p = pbase + pi * 16 + ml;
#pragma unroll
      for (int r = 0; r < 4; ++r) {
        int l = l0 + t0 + ti * 16 + g4 * 4 + r;
        ybuf[(size_t)l * D_INNER + h * HEADDIM + p] = accY[ti][pi][r];
      }
    }
}

// ------- RMSNorm + sigmoid(z) gate, emits gated y as FP16 (feeds f16 GEMM) ---
__launch_bounds__(256)
__global__ void rmsnorm_gate_split(const float* __restrict__ ybuf,
                                   const ushort* __restrict__ zx,
                                   const float* __restrict__ rms_w,
                                   ushort* __restrict__ yh) {
  const int row = blockIdx.x;
  const int t   = threadIdx.x;
  const float* y  = ybuf + (size_t)row * D_INNER;
  const ushort* z = zx   + (size_t)row * ZX_LD;      // z cols [0,2048)

  float4 a  = *(const float4*)(y + t * 8);
  float4 bq = *(const float4*)(y + t * 8 + 4);
  float ss = a.x * a.x + a.y * a.y + a.z * a.z + a.w * a.w +
             bq.x * bq.x + bq.y * bq.y + bq.z * bq.z + bq.w * bq.w;
#pragma unroll
  for (int off = 32; off > 0; off >>= 1) ss += __shfl_down(ss, off);
  __shared__ float red[4];
  if ((t & 63) == 0) red[t >> 6] = ss;
  __syncthreads();
  float tot = red[0] + red[1] + red[2] + red[3];
  float scale = rsqrtf(tot * (1.f / (float)D_INNER) + RMS_EPS);

  float vy[8] = {a.x, a.y, a.z, a.w, bq.x, bq.y, bq.z, bq.w};
  ushort4 zv0 = *(const ushort4*)(z + t * 8);
  ushort4 zv1 = *(const ushort4*)(z + t * 8 + 4);
  ushort zz[8] = {zv0.x, zv0.y, zv0.z, zv0.w, zv1.x, zv1.y, zv1.z, zv1.w};
  ushort hh[8];
#pragma unroll
  for (int jj = 0; jj < 8; ++jj) {
    int col = t * 8 + jj;
    float g = 1.f / (1.f + __expf(-bf2f(zz[jj])));
    float v = vy[jj] * scale * rms_w[col] * g;
    hh[jj] = f2h(v);
  }
  size_t o = (size_t)row * D_INNER + t * 8;
  *(ushort4*)(yh + o)     = make_ushort4(hh[0], hh[1], hh[2], hh[3]);
  *(ushort4*)(yh + o + 4) = make_ushort4(hh[4], hh[5], hh[6], hh[7]);
}

// ---------------- launch ----------------
// ws layout identical (129.8 MB). f16 planes overwrite unused bf16 regions:
// w1f16 = w1h rows [0,4224) (dt rows preserved), w2f16 = w2h, uf16 = ybuf
// overlay (dead until passA).
extern "C" void kernel_launch(void* const* d_in, const int* in_sizes, int n_in,
                              void* d_out, int out_size, void* d_ws, size_t ws_size,
                              hipStream_t stream) {
  const float* u         = (const float*)d_in[0];
  const float* in_proj_w = (const float*)d_in[1];
  const float* conv_w    = (const float*)d_in[2];
  const float* conv_b    = (const float*)d_in[3];
  const float* dt_bias   = (const float*)d_in[4];
  const float* A_log     = (const float*)d_in[5];
  const float* Dp        = (const float*)d_in[6];
  const float* rms_w     = (const float*)d_in[7];
  const float* out_w     = (const float*)d_in[8];
  float* out = (float*)d_out;

  float* ws    = (float*)d_ws;
  ushort* zxbc = (ushort*)ws;                                  // [4096, 4224] bf16
  float* dtb   = ws   + (size_t)SEQLEN * ZX_LD / 2;            // [4096, 16]
  float* dtp   = dtb  + (size_t)SEQLEN * NHEADS;               // [8, 4096, 16]
  float* ybuf  = dtp  + (size_t)8 * SEQLEN * NHEADS;           // [4096, 2048]
  float* Pc    = ybuf + (size_t)SEQLEN * D_INNER;              // [512]
  float* Sc    = Pc   + 512;                                   // [512, 8192]
  ushort* uh   = (ushort*)(Sc + (size_t)NHEADS * NCHUNK * HEADDIM * D_STATE);
  ushort* ul   = uh  + (size_t)SEQLEN * D_MODEL;
  ushort* w1h  = ul  + (size_t)SEQLEN * D_MODEL;
  ushort* w1l  = w1h + (size_t)D_IN_PROJ * D_MODEL;
  ushort* w2h  = w1l + (size_t)D_IN_PROJ * D_MODEL;
  ushort* w2l  = w2h + (size_t)D_MODEL * D_INNER;
  ushort* yh   = (ushort*)Sc;                                  // overlay Sc (dead)
  float* bconv = dtp;                                          // overlay dtp (dead)
  ushort* uf16 = (ushort*)ybuf;                                // overlay ybuf (pre-passA)

  // weight conversions (once per call): bf16 hi/lo for dt rows, f16 elsewhere
  {
    int n4 = D_IN_PROJ * D_MODEL / 4;
    cvt_split<<<(n4 + 255) / 256, 256, 0, stream>>>(in_proj_w, w1h, w1l, n4);
    int z4 = ZX_LD * D_MODEL / 4;     // overwrite rows [0,4224) of w1h with f16
    cvt_f16<<<(z4 + 255) / 256, 256, 0, stream>>>(in_proj_w, w1h, z4);
    int m4 = D_MODEL * D_INNER / 4;
    cvt_f16<<<(m4 + 255) / 256, 256, 0, stream>>>(out_w, w2h, m4);
  }

  for (int b = 0; b < BATCH; ++b) {
    const float* u_b  = u   + (size_t)b * SEQLEN * D_MODEL;
    float*      out_b = out + (size_t)b * SEQLEN * D_MODEL;

    // 0) u_b -> bf16 hi/lo + f16 plane in ONE pass (u read once)
    {
      int n4 = SEQLEN * D_MODEL / 4;
      cvt_u3<<<(n4 + 255) / 256, 256, 0, stream>>>(u_b, uh, ul, uf16, n4);
    }

    // 1) merged z|x|B|C GEMM — f16, single-buffered 128^2 @ 4 blocks/CU
    {
      dim3 g(40, SEQLEN / 128, 1);
      gemm_f16<128, 64, true, false><<<g, 256, 0, stream>>>(uf16, w1h, (float*)zxbc,
                                                            ZX_LD, SEQLEN, ZX_LD,
                                                            D_MODEL, D_MODEL);
    }
    // 1b) dt GEMM (3-term bf16, split-K=8): N=16, near-fp32 (feeds exponentials)
    {
      const ushort* bh = w1h + (size_t)ZX_LD * D_MODEL;
      const ushort* bl = w1l + (size_t)ZX_LD * D_MODEL;
      dim3 g(1, SEQLEN / 128, 8);
      gemm_bf16p<128, 32, true, false><<<g, 256, 0, stream>>>(uh, ul, bh, bl,
                                                          dtp, NHEADS, SEQLEN, NHEADS,
                                                          D_MODEL, D_MODEL / 8, 0);
      add_dt<<<(SEQLEN * NHEADS / 4 + 255) / 256, 256, 0, stream>>>(dtp, dtb);
    }

    // 2-4) SSD chunked scan on MFMA (f16 operands, p-split grids: 4 blocks/CU)
    passA_ssd<<<dim3(NHEADS * NCHUNK, 2), 256, 0, stream>>>(zxbc, dtb, conv_w, conv_b,
                                                            dt_bias, A_log, Sc, Pc,
                                                            ybuf, bconv);
    scan_passB<<<dim3(NHEADS, (HEADDIM * D_STATE) / 512), 512, 0, stream>>>(Sc, Pc);
    passC_ssd<<<dim3(NHEADS * NCHUNK, 2), 256, 0, stream>>>(zxbc, dtb, conv_w, conv_b,
                                                            dt_bias, A_log, Dp, Sc,
                                                            bconv, ybuf);

    // 5) RMSNorm + gate -> y f16 (overlays Sc, dead now)
    rmsnorm_gate_split<<<SEQLEN, 256, 0, stream>>>(ybuf, zxbc, rms_w, yh);

    // 6) out GEMM — NO split-K, BM=64: grid (8,64)=512 blocks = 2/CU (the
    //    residency PIPE was proven at, R5/R8), full K=2048/block, direct fp32
    //    write to out_b. Kills the 80MB/batch partials+add_out round-trip.
    //    (R9's 1-block/CU no-split-K regressed; this keeps 2/CU.)
    {
      dim3 g(D_MODEL / 128, SEQLEN / 64, 1);
      gemm_f16<64, 64, false, true><<<g, 256, 0, stream>>>(yh, w2h, out_b, D_MODEL,
                                                           SEQLEN, D_MODEL,
                                                           D_INNER, D_INNER);
    }
  }
}